// Round 3
// baseline (319.222 us; speedup 1.0000x reference)
//
#include <hip/hip_runtime.h>
#include <hip/hip_bf16.h>

// Problem constants
#define BB 2
#define TT 2048
#define DD 1024
#define HH 16
#define DH 64
#define RR 16
#define BT (BB*TT)      // 4096
#define BH (BB*HH)      // 32
#define D3 (3*DD)       // 3072

typedef __bf16 bf16x8 __attribute__((ext_vector_type(8)));
typedef float f32x4 __attribute__((ext_vector_type(4)));

__device__ __forceinline__ float bf2f(unsigned short u) {
  unsigned int v = ((unsigned int)u) << 16;
  return __builtin_bit_cast(float, v);
}
__device__ __forceinline__ unsigned short f2bf(float f) {
  unsigned int x = __builtin_bit_cast(unsigned int, f);
  unsigned int r = x + 0x7fffu + ((x >> 16) & 1u);
  return (unsigned short)(r >> 16);
}
__device__ __forceinline__ float rmax16(float v) {
#pragma unroll
  for (int off = 1; off < 16; off <<= 1) v = fmaxf(v, __shfl_xor(v, off, 64));
  return v;
}
__device__ __forceinline__ float rsum16(float v) {
#pragma unroll
  for (int off = 1; off < 16; off <<= 1) v += __shfl_xor(v, off, 64);
  return v;
}

#define NEG_BIG (-1e30f)

// async 16B global -> LDS (wave-uniform base + lane*16 dest; lane order must be contiguous)
__device__ __forceinline__ void async_copy16(const void* g, void* l) {
  __builtin_amdgcn_global_load_lds((const __attribute__((address_space(1))) void*)g,
                                   (__attribute__((address_space(3))) void*)l, 16, 0, 0);
}

// ---------------- fp32 -> bf16 elementwise convert (n multiple of 8) ----------------
__global__ __launch_bounds__(256) void cvt_f32_bf16(const float* __restrict__ in,
                                                    unsigned short* __restrict__ out,
                                                    int n) {
  int i = (blockIdx.x * 256 + threadIdx.x) * 8;
  if (i >= n) return;
  float4 a = *(const float4*)&in[i];
  float4 b = *(const float4*)&in[i + 4];
  unsigned short t[8] = {f2bf(a.x), f2bf(a.y), f2bf(a.z), f2bf(a.w),
                         f2bf(b.x), f2bf(b.y), f2bf(b.z), f2bf(b.w)};
  *(uint4*)&out[i] = *(const uint4*)t;
}

// ---------------- transpose + convert: fp32 (R x C) -> bf16 (C x R) -----------------
__global__ __launch_bounds__(256) void transpose_cvt(const float* __restrict__ in,
                                                     unsigned short* __restrict__ out,
                                                     int R, int C) {
  __shared__ float tile[32][33];
  const int tx = threadIdx.x, ty = threadIdx.y;
  const int x = blockIdx.x * 32 + tx;
  const int y0 = blockIdx.y * 32;
#pragma unroll
  for (int i = 0; i < 32; i += 8)
    tile[ty + i][tx] = in[(size_t)(y0 + ty + i) * C + x];
  __syncthreads();
  const int xo = y0 + tx;
  const int yo0 = blockIdx.x * 32;
#pragma unroll
  for (int i = 0; i < 32; i += 8)
    out[(size_t)(yo0 + ty + i) * R + xo] = f2bf(tile[tx][ty + i]);
}

// ---------------- bf16 GEMM (m97 structure): C[MxN] = A[MxK] * Bt[NxK]^T ------------
// 128x128 tile, BK=32, 256 threads = 4 waves in 2x2, 4x4 16x16 accs per wave.
// Staging via global_load_lds width=16 (LDS layout contiguous in lane order; no pad).
template <bool F32OUT>
__global__ __launch_bounds__(256) void gemm_bt(const unsigned short* __restrict__ A,
                                               const unsigned short* __restrict__ Bt,
                                               void* __restrict__ Cv,
                                               int M, int N, int K) {
  __shared__ __attribute__((aligned(16))) unsigned short As[128 * 32];
  __shared__ __attribute__((aligned(16))) unsigned short Bs[128 * 32];
  const int tid = threadIdx.x;
  const int lane = tid & 63;
  const int g = lane >> 4, c = lane & 15;
  const int wid = tid >> 6;
  const int wm = wid >> 1, wn = wid & 1;
  const int bm = blockIdx.y, bn = blockIdx.x;

  f32x4 acc[4][4] = {};

  const int e0 = tid * 8, e1 = (256 + tid) * 8;
  const int r0 = e0 >> 5, q0 = e0 & 31;
  const int r1 = e1 >> 5, q1 = e1 & 31;
  const unsigned short* Arow0 = &A[(size_t)(bm * 128 + r0) * K + q0];
  const unsigned short* Arow1 = &A[(size_t)(bm * 128 + r1) * K + q1];
  const unsigned short* Brow0 = &Bt[(size_t)(bn * 128 + r0) * K + q0];
  const unsigned short* Brow1 = &Bt[(size_t)(bn * 128 + r1) * K + q1];

  for (int k0 = 0; k0 < K; k0 += 32) {
    __syncthreads();
    async_copy16(Arow0 + k0, &As[e0]);
    async_copy16(Arow1 + k0, &As[e1]);
    async_copy16(Brow0 + k0, &Bs[e0]);
    async_copy16(Brow1 + k0, &Bs[e1]);
    __syncthreads();   // compiler drains vmcnt before s_barrier
    bf16x8 af[4];
#pragma unroll
    for (int mt = 0; mt < 4; mt++)
      af[mt] = *(const bf16x8*)&As[(wm * 64 + mt * 16 + c) * 32 + g * 8];
#pragma unroll
    for (int nt = 0; nt < 4; nt++) {
      bf16x8 bf = *(const bf16x8*)&Bs[(wn * 64 + nt * 16 + c) * 32 + g * 8];
#pragma unroll
      for (int mt = 0; mt < 4; mt++)
        acc[mt][nt] = __builtin_amdgcn_mfma_f32_16x16x32_bf16(af[mt], bf, acc[mt][nt], 0, 0, 0);
    }
  }
#pragma unroll
  for (int mt = 0; mt < 4; mt++)
#pragma unroll
    for (int nt = 0; nt < 4; nt++)
#pragma unroll
      for (int r = 0; r < 4; r++) {
        int row = bm * 128 + wm * 64 + mt * 16 + g * 4 + r;
        int col = bn * 128 + wn * 64 + nt * 16 + c;
        if (F32OUT)
          ((float*)Cv)[(size_t)row * N + col] = acc[mt][nt][r];
        else
          ((unsigned short*)Cv)[(size_t)row * N + col] = f2bf(acc[mt][nt][r]);
      }
}

// ---------------- LSR repack: q_lr (scaled, padded), k_lr (padded), V^T -------------
// grid (T/64, B*H), 256 threads. qkv is (B*T, 3072) bf16; Wq/Wk/core are fp32.
__global__ __launch_bounds__(256) void lsr_repack(const unsigned short* __restrict__ qkv,
                                                  const float* __restrict__ Wq,
                                                  const float* __restrict__ Wk,
                                                  const float* __restrict__ core,
                                                  unsigned short* __restrict__ qls,  // (BH, T, 32)
                                                  unsigned short* __restrict__ klr,  // (BH, T, 32)
                                                  unsigned short* __restrict__ vt) { // (BH, 64, T)
  const int bh = blockIdx.y, b = bh >> 4, h = bh & 15;
  const int t0 = blockIdx.x * 64;
  const int tid = threadIdx.x;
  __shared__ float Wq_s[64 * 16], Wk_s[64 * 16], core_s[16];
  __shared__ unsigned short q_s[64 * 64], k_s[64 * 64], v_s[64 * 64];

  for (int i = tid; i < 1024; i += 256) {
    Wq_s[i] = Wq[h * 1024 + i];
    Wk_s[i] = Wk[h * 1024 + i];
  }
  if (tid < 16) core_s[tid] = core[h * 16 + tid];
#pragma unroll
  for (int p = 0; p < 2; p++) {
    int e = (p * 256 + tid) * 8;
    int t = e >> 6, d = e & 63;
    size_t base = ((size_t)(b * TT + t0 + t)) * D3 + h * 64 + d;
    *(uint4*)&q_s[e] = *(const uint4*)&qkv[base];
    *(uint4*)&k_s[e] = *(const uint4*)&qkv[base + DD];
    *(uint4*)&v_s[e] = *(const uint4*)&qkv[base + 2 * DD];
  }
  __syncthreads();

#pragma unroll
  for (int itr = 0; itr < 4; itr++) {
    int idx = itr * 256 + tid;           // 0..1023
    int t = idx >> 4, r = idx & 15;
    float aq = 0.f, ak = 0.f;
#pragma unroll
    for (int d = 0; d < 64; d++) {
      aq += bf2f(q_s[t * 64 + d]) * Wq_s[d * 16 + r];
      ak += bf2f(k_s[t * 64 + d]) * Wk_s[d * 16 + r];
    }
    aq *= core_s[r] * 0.25f;             // core * 1/sqrt(R)
    size_t ob = ((size_t)bh * TT + t0 + t) * 32;
    qls[ob + r] = f2bf(aq);
    qls[ob + 16 + r] = 0;                // zero pad r=16..31
    klr[ob + r] = f2bf(ak);
    klr[ob + 16 + r] = 0;
  }
#pragma unroll
  for (int p = 0; p < 16; p++) {
    int idx = p * 256 + tid;             // 0..4095
    int d = idx >> 6, t = idx & 63;
    vt[((size_t)bh * 64 + d) * TT + t0 + t] = v_s[t * 64 + d];
  }
}

// ---------------- Flash attention over low-rank scores (v2) -------------------------
// grid (T/64, B*H), 256 threads = 4 waves; wave w owns q-rows [w*16, w*16+16) of the
// 64-row tile. Register-prefetch of next K/V tile overlaps compute. 44.8KB LDS -> 3 blk/CU.
__global__ __launch_bounds__(256) void flash_lsr(const unsigned short* __restrict__ qls,
                                                 const unsigned short* __restrict__ klr,
                                                 const unsigned short* __restrict__ vt,
                                                 unsigned short* __restrict__ attn) { // (B*T, 1024)
  const int it = blockIdx.x;            // 64-row q tile
  const int bh = blockIdx.y, b = bh >> 4, h = bh & 15;
  const int tid = threadIdx.x, lane = tid & 63, w = tid >> 6;
  const int g = lane >> 4, c = lane & 15;
  const int q0 = it * 64;
  __shared__ __attribute__((aligned(16))) unsigned short Ks[128 * 40];   // stride 40: 80B rows, 2-way (free)
  __shared__ __attribute__((aligned(16))) unsigned short Vs[64 * 136];
  __shared__ __attribute__((aligned(16))) unsigned short Ps[64 * 136];

  bf16x8 qf = *(const bf16x8*)&qls[((size_t)bh * TT + q0 + w * 16 + c) * 32 + g * 8];

  float mi[4], li[4];
  f32x4 oa[4] = {};
#pragma unroll
  for (int r = 0; r < 4; r++) { mi[r] = NEG_BIG; li[r] = 0.f; }
  const f32x4 zero = {0.f, 0.f, 0.f, 0.f};

  const int jt_max = (it * 64 + 63) >> 7;
  const int e0 = tid * 8, e1 = (256 + tid) * 8;
  const size_t kbase = (size_t)bh * TT * 32;
  const size_t vbase = (size_t)bh * 64 * TT;

  // prefetch jt=0 into registers
  uint4 kr0 = *(const uint4*)&klr[kbase + e0];
  uint4 kr1 = *(const uint4*)&klr[kbase + e1];
  uint4 vr[4];
#pragma unroll
  for (int p = 0; p < 4; p++) {
    int e = (p * 256 + tid) * 8;
    vr[p] = *(const uint4*)&vt[vbase + (size_t)(e >> 7) * TT + (e & 127)];
  }

  for (int jt = 0; jt <= jt_max; jt++) {
    __syncthreads();                     // prev-iter LDS consumers done
    *(uint4*)&Ks[(e0 >> 5) * 40 + (e0 & 31)] = kr0;
    *(uint4*)&Ks[(e1 >> 5) * 40 + (e1 & 31)] = kr1;
#pragma unroll
    for (int p = 0; p < 4; p++) {
      int e = (p * 256 + tid) * 8;
      *(uint4*)&Vs[(e >> 7) * 136 + (e & 127)] = vr[p];
    }
    __syncthreads();
    if (jt < jt_max) {                   // issue next-tile loads; they fly under compute
      const unsigned short* kp = &klr[kbase + (size_t)(jt + 1) * 128 * 32];
      kr0 = *(const uint4*)&kp[e0];
      kr1 = *(const uint4*)&kp[e1];
#pragma unroll
      for (int p = 0; p < 4; p++) {
        int e = (p * 256 + tid) * 8;
        vr[p] = *(const uint4*)&vt[vbase + (size_t)(e >> 7) * TT + (jt + 1) * 128 + (e & 127)];
      }
    }

    // S = Q_lr * K_lr^T  (128 cols per j-tile)
    f32x4 s[8];
#pragma unroll
    for (int nt = 0; nt < 8; nt++) {
      bf16x8 kf = *(const bf16x8*)&Ks[(nt * 16 + c) * 40 + g * 8];
      s[nt] = __builtin_amdgcn_mfma_f32_16x16x32_bf16(qf, kf, zero, 0, 0, 0);
    }
    if (jt == jt_max) {
#pragma unroll
      for (int nt = 0; nt < 8; nt++) {
        int colg = jt * 128 + nt * 16 + c;
#pragma unroll
        for (int r = 0; r < 4; r++) {
          int rowg = q0 + w * 16 + g * 4 + r;
          if (colg > rowg) s[nt][r] = NEG_BIG;
        }
      }
    }
    // online softmax (4 independent r-chains for ILP)
#pragma unroll
    for (int r = 0; r < 4; r++) {
      float rm = fmaxf(fmaxf(fmaxf(s[0][r], s[1][r]), fmaxf(s[2][r], s[3][r])),
                       fmaxf(fmaxf(s[4][r], s[5][r]), fmaxf(s[6][r], s[7][r])));
      rm = rmax16(rm);
      float mnew = fmaxf(mi[r], rm);
      float alpha = __expf(mi[r] - mnew);
      mi[r] = mnew;
      float rs = 0.f;
#pragma unroll
      for (int nt = 0; nt < 8; nt++) {
        float pv = __expf(s[nt][r] - mnew);
        s[nt][r] = pv;
        rs += pv;
      }
      rs = rsum16(rs);
      li[r] = li[r] * alpha + rs;
#pragma unroll
      for (int nd = 0; nd < 4; nd++) oa[nd][r] *= alpha;
      int prow = w * 16 + g * 4 + r;     // wave-private rows: no barrier needed
#pragma unroll
      for (int nt = 0; nt < 8; nt++)
        Ps[prow * 136 + nt * 16 + c] = f2bf(s[nt][r]);
    }
    // O += P * V
#pragma unroll
    for (int kk = 0; kk < 4; kk++) {
      bf16x8 pf = *(const bf16x8*)&Ps[(w * 16 + c) * 136 + kk * 32 + g * 8];
#pragma unroll
      for (int nd = 0; nd < 4; nd++) {
        bf16x8 vf = *(const bf16x8*)&Vs[(nd * 16 + c) * 136 + kk * 32 + g * 8];
        oa[nd] = __builtin_amdgcn_mfma_f32_16x16x32_bf16(pf, vf, oa[nd], 0, 0, 0);
      }
    }
  }

#pragma unroll
  for (int r = 0; r < 4; r++) {
    int row = q0 + w * 16 + g * 4 + r;
    float inv = 1.f / li[r];
#pragma unroll
    for (int nd = 0; nd < 4; nd++)
      attn[((size_t)b * TT + row) * DD + h * 64 + nd * 16 + c] = f2bf(oa[nd][r] * inv);
  }
}

extern "C" void kernel_launch(void* const* d_in, const int* in_sizes, int n_in,
                              void* d_out, int out_size, void* d_ws, size_t ws_size,
                              hipStream_t stream) {
  const float* x      = (const float*)d_in[0];  // (B,T,1024) fp32
  const float* W_qkv  = (const float*)d_in[1];  // (1024,3072) fp32
  const float* W_qlsr = (const float*)d_in[2];  // (16,64,16)  fp32
  const float* W_klsr = (const float*)d_in[3];  // (16,64,16)  fp32
  const float* core   = (const float*)d_in[4];  // (16,16)     fp32
  const float* W_o    = (const float*)d_in[5];  // (1024,1024) fp32
  float* out = (float*)d_out;                   // (B,T,1024)  fp32

  char* ws = (char*)d_ws;
  unsigned short* x_bf   = (unsigned short*)ws; ws += (size_t)BT * DD * 2;   // (4096,1024)
  unsigned short* Wqkv_t = (unsigned short*)ws; ws += (size_t)D3 * DD * 2;   // (3072,1024)
  unsigned short* Wo_t   = (unsigned short*)ws; ws += (size_t)DD * DD * 2;   // (1024,1024)
  unsigned short* qkv    = (unsigned short*)ws; ws += (size_t)BT * D3 * 2;   // (4096,3072)
  unsigned short* qls    = (unsigned short*)ws; ws += (size_t)BH * TT * 32 * 2;
  unsigned short* klr    = (unsigned short*)ws; ws += (size_t)BH * TT * 32 * 2;
  unsigned short* vt     = (unsigned short*)ws; ws += (size_t)BH * 64 * TT * 2;
  unsigned short* attn   = (unsigned short*)ws; ws += (size_t)BT * DD * 2;

  cvt_f32_bf16<<<(BT * DD) / (256 * 8), 256, 0, stream>>>(x, x_bf, BT * DD);
  transpose_cvt<<<dim3(D3 / 32, DD / 32), dim3(32, 8), 0, stream>>>(W_qkv, Wqkv_t, DD, D3);
  transpose_cvt<<<dim3(DD / 32, DD / 32), dim3(32, 8), 0, stream>>>(W_o, Wo_t, DD, DD);
  gemm_bt<false><<<dim3(D3 / 128, BT / 128), 256, 0, stream>>>(x_bf, Wqkv_t, qkv, BT, D3, DD);
  lsr_repack<<<dim3(TT / 64, BH), 256, 0, stream>>>(qkv, W_qlsr, W_klsr, core, qls, klr, vt);
  flash_lsr<<<dim3(TT / 64, BH), 256, 0, stream>>>(qls, klr, vt, attn);
  gemm_bt<true><<<dim3(DD / 128, BT / 128), 256, 0, stream>>>(attn, Wo_t, out, BT, DD, DD);
}

// Round 4
// 271.139 us; speedup vs baseline: 1.1773x; 1.1773x over previous
//
#include <hip/hip_runtime.h>
#include <hip/hip_bf16.h>

// Problem constants
#define BB 2
#define TT 2048
#define DD 1024
#define HH 16
#define DH 64
#define RR 16
#define BT (BB*TT)      // 4096
#define BH (BB*HH)      // 32
#define D3 (3*DD)       // 3072

typedef __bf16 bf16x8 __attribute__((ext_vector_type(8)));
typedef float f32x4 __attribute__((ext_vector_type(4)));

__device__ __forceinline__ float bf2f(unsigned short u) {
  unsigned int v = ((unsigned int)u) << 16;
  return __builtin_bit_cast(float, v);
}
__device__ __forceinline__ unsigned short f2bf(float f) {
  unsigned int x = __builtin_bit_cast(unsigned int, f);
  unsigned int r = x + 0x7fffu + ((x >> 16) & 1u);
  return (unsigned short)(r >> 16);
}
__device__ __forceinline__ unsigned pk2bf(float a, float b) {
  return (unsigned)f2bf(a) | ((unsigned)f2bf(b) << 16);
}

#define NEG_BIG (-1e30f)

// async 16B global -> LDS (wave-uniform base + lane*16 dest; lane order must be contiguous)
__device__ __forceinline__ void async_copy16(const void* g, void* l) {
  __builtin_amdgcn_global_load_lds((const __attribute__((address_space(1))) void*)g,
                                   (__attribute__((address_space(3))) void*)l, 16, 0, 0);
}

// ---------------- fp32 -> bf16 elementwise convert (n multiple of 8) ----------------
__global__ __launch_bounds__(256) void cvt_f32_bf16(const float* __restrict__ in,
                                                    unsigned short* __restrict__ out,
                                                    int n) {
  int i = (blockIdx.x * 256 + threadIdx.x) * 8;
  if (i >= n) return;
  float4 a = *(const float4*)&in[i];
  float4 b = *(const float4*)&in[i + 4];
  unsigned short t[8] = {f2bf(a.x), f2bf(a.y), f2bf(a.z), f2bf(a.w),
                         f2bf(b.x), f2bf(b.y), f2bf(b.z), f2bf(b.w)};
  *(uint4*)&out[i] = *(const uint4*)t;
}

// ---------------- transpose + convert: fp32 (R x C) -> bf16 (C x R) -----------------
__global__ __launch_bounds__(256) void transpose_cvt(const float* __restrict__ in,
                                                     unsigned short* __restrict__ out,
                                                     int R, int C) {
  __shared__ float tile[32][33];
  const int tx = threadIdx.x, ty = threadIdx.y;
  const int x = blockIdx.x * 32 + tx;
  const int y0 = blockIdx.y * 32;
#pragma unroll
  for (int i = 0; i < 32; i += 8)
    tile[ty + i][tx] = in[(size_t)(y0 + ty + i) * C + x];
  __syncthreads();
  const int xo = y0 + tx;
  const int yo0 = blockIdx.x * 32;
#pragma unroll
  for (int i = 0; i < 32; i += 8)
    out[(size_t)(yo0 + ty + i) * R + xo] = f2bf(tile[tx][ty + i]);
}

// ---------------- bf16 GEMM (m97 structure): C[MxN] = A[MxK] * Bt[NxK]^T ------------
template <bool F32OUT>
__global__ __launch_bounds__(256) void gemm_bt(const unsigned short* __restrict__ A,
                                               const unsigned short* __restrict__ Bt,
                                               void* __restrict__ Cv,
                                               int M, int N, int K) {
  __shared__ __attribute__((aligned(16))) unsigned short As[128 * 32];
  __shared__ __attribute__((aligned(16))) unsigned short Bs[128 * 32];
  const int tid = threadIdx.x;
  const int lane = tid & 63;
  const int g = lane >> 4, c = lane & 15;
  const int wid = tid >> 6;
  const int wm = wid >> 1, wn = wid & 1;
  const int bm = blockIdx.y, bn = blockIdx.x;

  f32x4 acc[4][4] = {};

  const int e0 = tid * 8, e1 = (256 + tid) * 8;
  const int r0 = e0 >> 5, q0 = e0 & 31;
  const int r1 = e1 >> 5, q1 = e1 & 31;
  const unsigned short* Arow0 = &A[(size_t)(bm * 128 + r0) * K + q0];
  const unsigned short* Arow1 = &A[(size_t)(bm * 128 + r1) * K + q1];
  const unsigned short* Brow0 = &Bt[(size_t)(bn * 128 + r0) * K + q0];
  const unsigned short* Brow1 = &Bt[(size_t)(bn * 128 + r1) * K + q1];

  for (int k0 = 0; k0 < K; k0 += 32) {
    __syncthreads();
    async_copy16(Arow0 + k0, &As[e0]);
    async_copy16(Arow1 + k0, &As[e1]);
    async_copy16(Brow0 + k0, &Bs[e0]);
    async_copy16(Brow1 + k0, &Bs[e1]);
    __syncthreads();
    bf16x8 af[4];
#pragma unroll
    for (int mt = 0; mt < 4; mt++)
      af[mt] = *(const bf16x8*)&As[(wm * 64 + mt * 16 + c) * 32 + g * 8];
#pragma unroll
    for (int nt = 0; nt < 4; nt++) {
      bf16x8 bf = *(const bf16x8*)&Bs[(wn * 64 + nt * 16 + c) * 32 + g * 8];
#pragma unroll
      for (int mt = 0; mt < 4; mt++)
        acc[mt][nt] = __builtin_amdgcn_mfma_f32_16x16x32_bf16(af[mt], bf, acc[mt][nt], 0, 0, 0);
    }
  }
#pragma unroll
  for (int mt = 0; mt < 4; mt++)
#pragma unroll
    for (int nt = 0; nt < 4; nt++)
#pragma unroll
      for (int r = 0; r < 4; r++) {
        int row = bm * 128 + wm * 64 + mt * 16 + g * 4 + r;
        int col = bn * 128 + wn * 64 + nt * 16 + c;
        if (F32OUT)
          ((float*)Cv)[(size_t)row * N + col] = acc[mt][nt][r];
        else
          ((unsigned short*)Cv)[(size_t)row * N + col] = f2bf(acc[mt][nt][r]);
      }
}

// ---------------- LSR repack: q_lr (scaled, padded), k_lr (padded), V^T -------------
__global__ __launch_bounds__(256) void lsr_repack(const unsigned short* __restrict__ qkv,
                                                  const float* __restrict__ Wq,
                                                  const float* __restrict__ Wk,
                                                  const float* __restrict__ core,
                                                  unsigned short* __restrict__ qls,  // (BH, T, 32)
                                                  unsigned short* __restrict__ klr,  // (BH, T, 32)
                                                  unsigned short* __restrict__ vt) { // (BH, 64, T)
  const int bh = blockIdx.y, b = bh >> 4, h = bh & 15;
  const int t0 = blockIdx.x * 64;
  const int tid = threadIdx.x;
  __shared__ float Wq_s[64 * 16], Wk_s[64 * 16], core_s[16];
  __shared__ unsigned short q_s[64 * 64], k_s[64 * 64], v_s[64 * 64];

  for (int i = tid; i < 1024; i += 256) {
    Wq_s[i] = Wq[h * 1024 + i];
    Wk_s[i] = Wk[h * 1024 + i];
  }
  if (tid < 16) core_s[tid] = core[h * 16 + tid];
#pragma unroll
  for (int p = 0; p < 2; p++) {
    int e = (p * 256 + tid) * 8;
    int t = e >> 6, d = e & 63;
    size_t base = ((size_t)(b * TT + t0 + t)) * D3 + h * 64 + d;
    *(uint4*)&q_s[e] = *(const uint4*)&qkv[base];
    *(uint4*)&k_s[e] = *(const uint4*)&qkv[base + DD];
    *(uint4*)&v_s[e] = *(const uint4*)&qkv[base + 2 * DD];
  }
  __syncthreads();

#pragma unroll
  for (int itr = 0; itr < 4; itr++) {
    int idx = itr * 256 + tid;           // 0..1023
    int t = idx >> 4, r = idx & 15;
    float aq = 0.f, ak = 0.f;
#pragma unroll
    for (int d = 0; d < 64; d++) {
      aq += bf2f(q_s[t * 64 + d]) * Wq_s[d * 16 + r];
      ak += bf2f(k_s[t * 64 + d]) * Wk_s[d * 16 + r];
    }
    aq *= core_s[r] * 0.25f;             // core * 1/sqrt(R)
    size_t ob = ((size_t)bh * TT + t0 + t) * 32;
    qls[ob + r] = f2bf(aq);
    qls[ob + 16 + r] = 0;                // zero pad r=16..31
    klr[ob + r] = f2bf(ak);
    klr[ob + 16 + r] = 0;
  }
#pragma unroll
  for (int p = 0; p < 16; p++) {
    int idx = p * 256 + tid;             // 0..4095
    int d = idx >> 6, t = idx & 63;
    vt[((size_t)bh * 64 + d) * TT + t0 + t] = v_s[t * 64 + d];
  }
}

// ---------------- Flash attention v3: S^T + shuffle-PV, paired causal tiles ---------
// grid (16, BH), 256 thr = 4 waves. Block z handles 64-row Q-tiles z and 31-z in ONE
// j-loop (A range subset of B) -> uniform 17 tile-computes, staging shared.
// Wave w owns q-cols [w*16, w*16+16). S computed TRANSPOSED: per-lane scores all for
// one q -> softmax = 2 shuffles; P^T built via in-register shuffles (no Ps LDS).
__global__ __launch_bounds__(256) void flash_lsr(const unsigned short* __restrict__ qls,
                                                 const unsigned short* __restrict__ klr,
                                                 const unsigned short* __restrict__ vt,
                                                 unsigned short* __restrict__ attn) { // (B*T, 1024)
  const int z = blockIdx.x;             // 0..15
  const int bh = blockIdx.y, b = bh >> 4, h = bh & 15;
  const int tid = threadIdx.x, lane = tid & 63, w = tid >> 6;
  const int g = lane >> 4, c = lane & 15;
  const int q0A = z * 64, q0B = (31 - z) * 64;
  const int jmaxA = (q0A + 63) >> 7, jmaxB = (q0B + 63) >> 7;

  __shared__ __attribute__((aligned(16))) unsigned short Ks[128 * 40];   // 10.0 KB
  __shared__ __attribute__((aligned(16))) unsigned short Vs[64 * 136];   // 17.0 KB

  const size_t qbase = (size_t)bh * TT;
  bf16x8 qfA = *(const bf16x8*)&qls[(qbase + q0A + w * 16 + c) * 32 + g * 8];
  bf16x8 qfB = *(const bf16x8*)&qls[(qbase + q0B + w * 16 + c) * 32 + g * 8];
  const int qgA = q0A + w * 16 + c, qgB = q0B + w * 16 + c;
  float miA = NEG_BIG, liA = 0.f, miB = NEG_BIG, liB = 0.f;
  f32x4 oaA[4] = {}, oaB[4] = {};
  const f32x4 zero = {0.f, 0.f, 0.f, 0.f};

  const int e0 = tid * 8, e1 = (256 + tid) * 8;
  const size_t kbase = (size_t)bh * TT * 32;
  const size_t vbase = (size_t)bh * 64 * TT;

  // prefetch j-tile 0
  uint4 kr0 = *(const uint4*)&klr[kbase + e0];
  uint4 kr1 = *(const uint4*)&klr[kbase + e1];
  uint4 vr[4];
#pragma unroll
  for (int p = 0; p < 4; p++) {
    int e = (p * 256 + tid) * 8;
    vr[p] = *(const uint4*)&vt[vbase + (size_t)(e >> 7) * TT + (e & 127)];
  }

  const int la = ((g & 1) * 2) * 16 + c;  // source lane (g' = (g&1)*2)
  const int lb = la + 16;                  // source lane (g' = (g&1)*2+1)
  const bool sel = (g >> 1) != 0;

  // one Q-tile's update against the staged j-tile
  auto compute_tile = [&](const bf16x8& qf, f32x4* oa, float& mi, float& li,
                          int qg, bool diag, int jt) {
    f32x4 s[8];
#pragma unroll
    for (int nt = 0; nt < 8; nt++) {
      bf16x8 kf = *(const bf16x8*)&Ks[(nt * 16 + c) * 40 + g * 8];
      s[nt] = __builtin_amdgcn_mfma_f32_16x16x32_bf16(kf, qf, zero, 0, 0, 0);  // S^T
    }
    if (diag) {
#pragma unroll
      for (int nt = 0; nt < 8; nt++)
#pragma unroll
        for (int r = 0; r < 4; r++) {
          int jg = jt * 128 + nt * 16 + g * 4 + r;
          if (jg > qg) s[nt][r] = NEG_BIG;
        }
    }
    // max over this lane's 32 scores (all same q), then across g-lanes
    f32x4 vm = s[0];
#pragma unroll
    for (int nt = 1; nt < 8; nt++)
#pragma unroll
      for (int r = 0; r < 4; r++) vm[r] = fmaxf(vm[r], s[nt][r]);
    float rm = fmaxf(fmaxf(vm[0], vm[1]), fmaxf(vm[2], vm[3]));
    rm = fmaxf(rm, __shfl_xor(rm, 16, 64));
    rm = fmaxf(rm, __shfl_xor(rm, 32, 64));
    float mnew = fmaxf(mi, rm);
    float alpha = __expf(mi - mnew);
    mi = mnew;
    f32x4 vs = zero;
#pragma unroll
    for (int nt = 0; nt < 8; nt++)
#pragma unroll
      for (int r = 0; r < 4; r++) {
        float pv = __expf(s[nt][r] - mnew);
        s[nt][r] = pv;
        vs[r] += pv;
      }
    float rs = (vs[0] + vs[1]) + (vs[2] + vs[3]);
    rs += __shfl_xor(rs, 16, 64);
    rs += __shfl_xor(rs, 32, 64);
    li = li * alpha + rs;
#pragma unroll
    for (int nd = 0; nd < 4; nd++)
#pragma unroll
      for (int r = 0; r < 4; r++) oa[nd][r] *= alpha;
    // pack P^T fragments: pk[2nt]=(r0,r1), pk[2nt+1]=(r2,r3)
    unsigned pk[16];
#pragma unroll
    for (int nt = 0; nt < 8; nt++) {
      pk[2 * nt] = pk2bf(s[nt][0], s[nt][1]);
      pk[2 * nt + 1] = pk2bf(s[nt][2], s[nt][3]);
    }
    // PV: O^T[d][q] += V^T * P^T ; B-frag for kk from lanes la/lb, tile 2kk+(g>>1)
#pragma unroll
    for (int kk = 0; kk < 4; kk++) {
      unsigned a0 = (unsigned)__shfl((int)pk[4 * kk + 0], la, 64);
      unsigned a1 = (unsigned)__shfl((int)pk[4 * kk + 1], la, 64);
      unsigned a2 = (unsigned)__shfl((int)pk[4 * kk + 2], la, 64);
      unsigned a3 = (unsigned)__shfl((int)pk[4 * kk + 3], la, 64);
      unsigned b0 = (unsigned)__shfl((int)pk[4 * kk + 0], lb, 64);
      unsigned b1 = (unsigned)__shfl((int)pk[4 * kk + 1], lb, 64);
      unsigned b2 = (unsigned)__shfl((int)pk[4 * kk + 2], lb, 64);
      unsigned b3 = (unsigned)__shfl((int)pk[4 * kk + 3], lb, 64);
      uint4 fw;
      fw.x = sel ? a2 : a0;   // jj 0,1
      fw.y = sel ? a3 : a1;   // jj 2,3
      fw.z = sel ? b2 : b0;   // jj 4,5
      fw.w = sel ? b3 : b1;   // jj 6,7
      bf16x8 pf = __builtin_bit_cast(bf16x8, fw);
#pragma unroll
      for (int nd = 0; nd < 4; nd++) {
        bf16x8 vf = *(const bf16x8*)&Vs[(nd * 16 + c) * 136 + kk * 32 + g * 8];
        oa[nd] = __builtin_amdgcn_mfma_f32_16x16x32_bf16(vf, pf, oa[nd], 0, 0, 0);
      }
    }
  };

  for (int jt = 0; jt <= jmaxB; jt++) {
    __syncthreads();
    *(uint4*)&Ks[(e0 >> 5) * 40 + (e0 & 31)] = kr0;
    *(uint4*)&Ks[(e1 >> 5) * 40 + (e1 & 31)] = kr1;
#pragma unroll
    for (int p = 0; p < 4; p++) {
      int e = (p * 256 + tid) * 8;
      *(uint4*)&Vs[(e >> 7) * 136 + (e & 127)] = vr[p];
    }
    __syncthreads();
    if (jt < jmaxB) {                    // prefetch next tile; flies under compute
      const unsigned short* kp = &klr[kbase + (size_t)(jt + 1) * 128 * 32];
      kr0 = *(const uint4*)&kp[e0];
      kr1 = *(const uint4*)&kp[e1];
#pragma unroll
      for (int p = 0; p < 4; p++) {
        int e = (p * 256 + tid) * 8;
        vr[p] = *(const uint4*)&vt[vbase + (size_t)(e >> 7) * TT + (jt + 1) * 128 + (e & 127)];
      }
    }
    compute_tile(qfB, oaB, miB, liB, qgB, jt == jmaxB, jt);
    if (jt <= jmaxA) compute_tile(qfA, oaA, miA, liA, qgA, jt == jmaxA, jt);
  }

  // epilogue: transpose O^T -> O via LDS (reuse Vs as 64x68 f32), fold 1/li
  float* To = (float*)Vs;
#pragma unroll
  for (int phase = 0; phase < 2; phase++) {
    const f32x4* oa = phase ? oaA : oaB;
    float li = phase ? liA : liB;
    int q0 = phase ? q0A : q0B;
    float inv = 1.f / li;
    __syncthreads();
#pragma unroll
    for (int nd = 0; nd < 4; nd++)
#pragma unroll
      for (int r = 0; r < 4; r++)
        To[(w * 16 + c) * 68 + nd * 16 + g * 4 + r] = oa[nd][r] * inv;
    __syncthreads();
    {
      int ql = tid >> 2, ch = (tid & 3) * 16;
      const float* src = &To[ql * 68 + ch];
      float4 f0 = *(const float4*)&src[0];
      float4 f1 = *(const float4*)&src[4];
      float4 f2 = *(const float4*)&src[8];
      float4 f3 = *(const float4*)&src[12];
      unsigned short tmp[16] = {
        f2bf(f0.x), f2bf(f0.y), f2bf(f0.z), f2bf(f0.w),
        f2bf(f1.x), f2bf(f1.y), f2bf(f1.z), f2bf(f1.w),
        f2bf(f2.x), f2bf(f2.y), f2bf(f2.z), f2bf(f2.w),
        f2bf(f3.x), f2bf(f3.y), f2bf(f3.z), f2bf(f3.w)};
      unsigned short* dst = &attn[((size_t)b * TT + q0 + ql) * DD + h * 64 + ch];
      *(uint4*)&dst[0] = *(const uint4*)&tmp[0];
      *(uint4*)&dst[8] = *(const uint4*)&tmp[8];
    }
  }
}

extern "C" void kernel_launch(void* const* d_in, const int* in_sizes, int n_in,
                              void* d_out, int out_size, void* d_ws, size_t ws_size,
                              hipStream_t stream) {
  const float* x      = (const float*)d_in[0];  // (B,T,1024) fp32
  const float* W_qkv  = (const float*)d_in[1];  // (1024,3072) fp32
  const float* W_qlsr = (const float*)d_in[2];  // (16,64,16)  fp32
  const float* W_klsr = (const float*)d_in[3];  // (16,64,16)  fp32
  const float* core   = (const float*)d_in[4];  // (16,16)     fp32
  const float* W_o    = (const float*)d_in[5];  // (1024,1024) fp32
  float* out = (float*)d_out;                   // (B,T,1024)  fp32

  char* ws = (char*)d_ws;
  unsigned short* x_bf   = (unsigned short*)ws; ws += (size_t)BT * DD * 2;   // (4096,1024)
  unsigned short* Wqkv_t = (unsigned short*)ws; ws += (size_t)D3 * DD * 2;   // (3072,1024)
  unsigned short* Wo_t   = (unsigned short*)ws; ws += (size_t)DD * DD * 2;   // (1024,1024)
  unsigned short* qkv    = (unsigned short*)ws; ws += (size_t)BT * D3 * 2;   // (4096,3072)
  unsigned short* qls    = (unsigned short*)ws; ws += (size_t)BH * TT * 32 * 2;
  unsigned short* klr    = (unsigned short*)ws; ws += (size_t)BH * TT * 32 * 2;
  unsigned short* vt     = (unsigned short*)ws; ws += (size_t)BH * 64 * TT * 2;
  unsigned short* attn   = (unsigned short*)ws; ws += (size_t)BT * DD * 2;

  cvt_f32_bf16<<<(BT * DD) / (256 * 8), 256, 0, stream>>>(x, x_bf, BT * DD);
  transpose_cvt<<<dim3(D3 / 32, DD / 32), dim3(32, 8), 0, stream>>>(W_qkv, Wqkv_t, DD, D3);
  transpose_cvt<<<dim3(DD / 32, DD / 32), dim3(32, 8), 0, stream>>>(W_o, Wo_t, DD, DD);
  gemm_bt<false><<<dim3(D3 / 128, BT / 128), 256, 0, stream>>>(x_bf, Wqkv_t, qkv, BT, D3, DD);
  lsr_repack<<<dim3(TT / 64, BH), 256, 0, stream>>>(qkv, W_qlsr, W_klsr, core, qls, klr, vt);
  flash_lsr<<<dim3(16, BH), 256, 0, stream>>>(qls, klr, vt, attn);
  gemm_bt<true><<<dim3(DD / 128, BT / 128), 256, 0, stream>>>(attn, Wo_t, out, BT, DD, DD);
}

// Round 6
// 258.817 us; speedup vs baseline: 1.2334x; 1.0476x over previous
//
#include <hip/hip_runtime.h>
#include <hip/hip_bf16.h>

// Problem constants
#define BB 2
#define TT 2048
#define DD 1024
#define HH 16
#define DH 64
#define RR 16
#define BT (BB*TT)      // 4096
#define BH (BB*HH)      // 32
#define D3 (3*DD)       // 3072

typedef __bf16 bf16x8 __attribute__((ext_vector_type(8)));
typedef float f32x4 __attribute__((ext_vector_type(4)));
typedef short short4v __attribute__((ext_vector_type(4)));

__device__ __forceinline__ float bf2f(unsigned short u) {
  unsigned int v = ((unsigned int)u) << 16;
  return __builtin_bit_cast(float, v);
}
__device__ __forceinline__ unsigned short f2bf(float f) {
  unsigned int x = __builtin_bit_cast(unsigned int, f);
  unsigned int r = x + 0x7fffu + ((x >> 16) & 1u);
  return (unsigned short)(r >> 16);
}
// 4x f32 -> 4x bf16 (round-to-nearest-even), packed into a K=16 MFMA A-frag
__device__ __forceinline__ short4v pack_bf16x4(float a, float b, float c, float d) {
  uint2 u;
  u.x = (unsigned)f2bf(a) | ((unsigned)f2bf(b) << 16);
  u.y = (unsigned)f2bf(c) | ((unsigned)f2bf(d) << 16);
  return __builtin_bit_cast(short4v, u);
}

#define NEG_BIG (-1e30f)

// async 16B global -> LDS (wave-uniform base + lane*16 dest; lane order must be contiguous)
__device__ __forceinline__ void async_copy16(const void* g, void* l) {
  __builtin_amdgcn_global_load_lds((const __attribute__((address_space(1))) void*)g,
                                   (__attribute__((address_space(3))) void*)l, 16, 0, 0);
}

// ---------------- fp32 -> bf16 elementwise convert (n multiple of 8) ----------------
__global__ __launch_bounds__(256) void cvt_f32_bf16(const float* __restrict__ in,
                                                    unsigned short* __restrict__ out,
                                                    int n) {
  int i = (blockIdx.x * 256 + threadIdx.x) * 8;
  if (i >= n) return;
  float4 a = *(const float4*)&in[i];
  float4 b = *(const float4*)&in[i + 4];
  unsigned short t[8] = {f2bf(a.x), f2bf(a.y), f2bf(a.z), f2bf(a.w),
                         f2bf(b.x), f2bf(b.y), f2bf(b.z), f2bf(b.w)};
  *(uint4*)&out[i] = *(const uint4*)t;
}

// ---------------- transpose + convert: fp32 (R x C) -> bf16 (C x R) -----------------
__global__ __launch_bounds__(256) void transpose_cvt(const float* __restrict__ in,
                                                     unsigned short* __restrict__ out,
                                                     int R, int C) {
  __shared__ float tile[32][33];
  const int tx = threadIdx.x, ty = threadIdx.y;
  const int x = blockIdx.x * 32 + tx;
  const int y0 = blockIdx.y * 32;
#pragma unroll
  for (int i = 0; i < 32; i += 8)
    tile[ty + i][tx] = in[(size_t)(y0 + ty + i) * C + x];
  __syncthreads();
  const int xo = y0 + tx;
  const int yo0 = blockIdx.x * 32;
#pragma unroll
  for (int i = 0; i < 32; i += 8)
    out[(size_t)(yo0 + ty + i) * R + xo] = f2bf(tile[tx][ty + i]);
}

// ---------------- bf16 GEMM (m97 structure): C[MxN] = A[MxK] * Bt[NxK]^T ------------
template <bool F32OUT>
__global__ __launch_bounds__(256) void gemm_bt(const unsigned short* __restrict__ A,
                                               const unsigned short* __restrict__ Bt,
                                               void* __restrict__ Cv,
                                               int M, int N, int K) {
  __shared__ __attribute__((aligned(16))) unsigned short As[128 * 32];
  __shared__ __attribute__((aligned(16))) unsigned short Bs[128 * 32];
  const int tid = threadIdx.x;
  const int lane = tid & 63;
  const int g = lane >> 4, c = lane & 15;
  const int wid = tid >> 6;
  const int wm = wid >> 1, wn = wid & 1;
  const int bm = blockIdx.y, bn = blockIdx.x;

  f32x4 acc[4][4] = {};

  const int e0 = tid * 8, e1 = (256 + tid) * 8;
  const int r0 = e0 >> 5, q0 = e0 & 31;
  const int r1 = e1 >> 5, q1 = e1 & 31;
  const unsigned short* Arow0 = &A[(size_t)(bm * 128 + r0) * K + q0];
  const unsigned short* Arow1 = &A[(size_t)(bm * 128 + r1) * K + q1];
  const unsigned short* Brow0 = &Bt[(size_t)(bn * 128 + r0) * K + q0];
  const unsigned short* Brow1 = &Bt[(size_t)(bn * 128 + r1) * K + q1];

  for (int k0 = 0; k0 < K; k0 += 32) {
    __syncthreads();
    async_copy16(Arow0 + k0, &As[e0]);
    async_copy16(Arow1 + k0, &As[e1]);
    async_copy16(Brow0 + k0, &Bs[e0]);
    async_copy16(Brow1 + k0, &Bs[e1]);
    __syncthreads();
    bf16x8 af[4];
#pragma unroll
    for (int mt = 0; mt < 4; mt++)
      af[mt] = *(const bf16x8*)&As[(wm * 64 + mt * 16 + c) * 32 + g * 8];
#pragma unroll
    for (int nt = 0; nt < 4; nt++) {
      bf16x8 bf = *(const bf16x8*)&Bs[(wn * 64 + nt * 16 + c) * 32 + g * 8];
#pragma unroll
      for (int mt = 0; mt < 4; mt++)
        acc[mt][nt] = __builtin_amdgcn_mfma_f32_16x16x32_bf16(af[mt], bf, acc[mt][nt], 0, 0, 0);
    }
  }
#pragma unroll
  for (int mt = 0; mt < 4; mt++)
#pragma unroll
    for (int nt = 0; nt < 4; nt++)
#pragma unroll
      for (int r = 0; r < 4; r++) {
        int row = bm * 128 + wm * 64 + mt * 16 + g * 4 + r;
        int col = bn * 128 + wn * 64 + nt * 16 + c;
        if (F32OUT)
          ((float*)Cv)[(size_t)row * N + col] = acc[mt][nt][r];
        else
          ((unsigned short*)Cv)[(size_t)row * N + col] = f2bf(acc[mt][nt][r]);
      }
}

// ---------------- LSR repack: q_lr (scaled, padded), k_lr (padded), V swizzled ------
// vt layout: (BH, T/4, 64, 4) = per 4-key group, all 64 d, then key&3. 16KB per
// 128-key tile, contiguous -> flash stages it with one coalesced copy.
__global__ __launch_bounds__(256) void lsr_repack(const unsigned short* __restrict__ qkv,
                                                  const float* __restrict__ Wq,
                                                  const float* __restrict__ Wk,
                                                  const float* __restrict__ core,
                                                  unsigned short* __restrict__ qls,  // (BH, T, 32)
                                                  unsigned short* __restrict__ klr,  // (BH, T, 32)
                                                  unsigned short* __restrict__ vt) { // (BH, T/4, 64, 4)
  const int bh = blockIdx.y, b = bh >> 4, h = bh & 15;
  const int t0 = blockIdx.x * 64;
  const int tid = threadIdx.x;
  __shared__ float Wq_s[64 * 16], Wk_s[64 * 16], core_s[16];
  __shared__ unsigned short q_s[64 * 64], k_s[64 * 64], v_s[64 * 64];

  for (int i = tid; i < 1024; i += 256) {
    Wq_s[i] = Wq[h * 1024 + i];
    Wk_s[i] = Wk[h * 1024 + i];
  }
  if (tid < 16) core_s[tid] = core[h * 16 + tid];
#pragma unroll
  for (int p = 0; p < 2; p++) {
    int e = (p * 256 + tid) * 8;
    int t = e >> 6, d = e & 63;
    size_t base = ((size_t)(b * TT + t0 + t)) * D3 + h * 64 + d;
    *(uint4*)&q_s[e] = *(const uint4*)&qkv[base];
    *(uint4*)&k_s[e] = *(const uint4*)&qkv[base + DD];
    *(uint4*)&v_s[e] = *(const uint4*)&qkv[base + 2 * DD];
  }
  __syncthreads();

#pragma unroll
  for (int itr = 0; itr < 4; itr++) {
    int idx = itr * 256 + tid;           // 0..1023
    int t = idx >> 4, r = idx & 15;
    float aq = 0.f, ak = 0.f;
#pragma unroll
    for (int d = 0; d < 64; d++) {
      aq += bf2f(q_s[t * 64 + d]) * Wq_s[d * 16 + r];
      ak += bf2f(k_s[t * 64 + d]) * Wk_s[d * 16 + r];
    }
    aq *= core_s[r] * 0.25f;             // core * 1/sqrt(R)
    size_t ob = ((size_t)bh * TT + t0 + t) * 32;
    qls[ob + r] = f2bf(aq);
    qls[ob + 16 + r] = 0;                // zero pad r=16..31
    klr[ob + r] = f2bf(ak);
    klr[ob + 16 + r] = 0;
  }
  // V swizzled write: vt[bh][(t0+t)>>2][d][t&3]
#pragma unroll
  for (int p = 0; p < 16; p++) {
    int idx = p * 256 + tid;             // 0..4095
    int tq = idx >> 8;                   // 0..15
    int rem = idx & 255;
    int d = rem >> 2, tr = rem & 3;
    vt[((size_t)bh * (TT / 4) + (t0 >> 2) + tq) * 256 + rem] = v_s[(tq * 4 + tr) * 64 + d];
  }
}

// ---------------- Flash attention v4: S^T -> direct K=16 PV, dbuf, 1 barrier/iter ---
// grid (16, BH), 256 thr = 4 waves. Block z handles 64-row Q-tiles z and 31-z.
// S computed transposed (lane (g,c): P[q=c][key=nt*16+g*4+r]) == A-operand layout of
// mfma_f32_16x16x16_bf16 -> PV consumes scores straight from registers; no Ps LDS,
// no shuffle transform, output lands in natural O[q][d] orientation.
__global__ __launch_bounds__(256) void flash_lsr(const unsigned short* __restrict__ qls,
                                                 const unsigned short* __restrict__ klr,
                                                 const unsigned short* __restrict__ vt,
                                                 unsigned short* __restrict__ attn) { // (B*T, 1024)
  const int z = blockIdx.x;             // 0..15
  const int bh = blockIdx.y, b = bh >> 4, h = bh & 15;
  const int tid = threadIdx.x, lane = tid & 63, w = tid >> 6;
  const int g = lane >> 4, c = lane & 15;
  const int q0A = z * 64, q0B = (31 - z) * 64;
  const int jmaxA = (q0A + 63) >> 7, jmaxB = (q0B + 63) >> 7;

  __shared__ __attribute__((aligned(16))) unsigned short Ks[2][128 * 40];  // 2x10.0 KB
  __shared__ __attribute__((aligned(16))) unsigned short Vs[2][32 * 264];  // 2x16.5 KB (row pad 256->264)

  const size_t qbase = (size_t)bh * TT;
  bf16x8 qfA = *(const bf16x8*)&qls[(qbase + q0A + w * 16 + c) * 32 + g * 8];
  bf16x8 qfB = *(const bf16x8*)&qls[(qbase + q0B + w * 16 + c) * 32 + g * 8];
  const int qgA = q0A + w * 16 + c, qgB = q0B + w * 16 + c;
  float miA = NEG_BIG, liA = 0.f, miB = NEG_BIG, liB = 0.f;
  f32x4 oaA[4] = {}, oaB[4] = {};
  const f32x4 zero = {0.f, 0.f, 0.f, 0.f};

  const int e0 = tid * 8, e1 = (256 + tid) * 8;
  const size_t kbase = (size_t)bh * TT * 32;
  const size_t vbase = (size_t)bh * (TT / 4) * 256;  // swizzled V, 8192 el per 128-key tile
  const int srcl = g * 16 + g * 4;       // broadcast source base: lane with c == g*4+r

  // prefetch j-tile 0 into registers
  uint4 kr0 = *(const uint4*)&klr[kbase + e0];
  uint4 kr1 = *(const uint4*)&klr[kbase + e1];
  uint4 vr[4];
#pragma unroll
  for (int p = 0; p < 4; p++)
    vr[p] = *(const uint4*)&vt[vbase + (p * 256 + tid) * 8];

  // one Q-tile's update against the staged j-tile (parity pb)
  auto compute_tile = [&](const bf16x8& qf, f32x4* oa, float& mi, float& li,
                          int qg, bool diag, int jt, int pb) {
    const unsigned short* Kb = Ks[pb];
    const unsigned short* Vb = Vs[pb];
    f32x4 s[8];
#pragma unroll
    for (int nt = 0; nt < 8; nt++) {
      bf16x8 kf = *(const bf16x8*)&Kb[(nt * 16 + c) * 40 + g * 8];
      s[nt] = __builtin_amdgcn_mfma_f32_16x16x32_bf16(kf, qf, zero, 0, 0, 0);  // S^T
    }
    if (diag) {
#pragma unroll
      for (int nt = 0; nt < 8; nt++)
#pragma unroll
        for (int r = 0; r < 4; r++) {
          int jg = jt * 128 + nt * 16 + g * 4 + r;
          if (jg > qg) s[nt][r] = NEG_BIG;
        }
    }
    // this lane's 32 scores all belong to q=c; reduce across the 4 c-sharing lanes
    f32x4 vm = s[0];
#pragma unroll
    for (int nt = 1; nt < 8; nt++)
#pragma unroll
      for (int r = 0; r < 4; r++) vm[r] = fmaxf(vm[r], s[nt][r]);
    float rm = fmaxf(fmaxf(vm[0], vm[1]), fmaxf(vm[2], vm[3]));
    rm = fmaxf(rm, __shfl_xor(rm, 16, 64));
    rm = fmaxf(rm, __shfl_xor(rm, 32, 64));
    float mnew = fmaxf(mi, rm);
    float alpha = __expf(mi - mnew);
    mi = mnew;
    f32x4 vs = zero;
#pragma unroll
    for (int nt = 0; nt < 8; nt++)
#pragma unroll
      for (int r = 0; r < 4; r++) {
        float pv = __expf(s[nt][r] - mnew);
        s[nt][r] = pv;
        vs[r] += pv;
      }
    float rs = (vs[0] + vs[1]) + (vs[2] + vs[3]);
    rs += __shfl_xor(rs, 16, 64);
    rs += __shfl_xor(rs, 32, 64);
    li = li * alpha + rs;
    // alpha is per-q(=c); accumulator rows are q=g*4+r -> redistribute (4 bpermutes)
    float av[4];
#pragma unroll
    for (int r = 0; r < 4; r++) av[r] = __shfl(alpha, srcl + r, 64);
#pragma unroll
    for (int nd = 0; nd < 4; nd++)
#pragma unroll
      for (int r = 0; r < 4; r++) oa[nd][r] *= av[r];
    // PV: O[q][d] += P * V, K=16 MFMAs; A-frag = packed scores (direct reuse)
#pragma unroll
    for (int kc = 0; kc < 8; kc++) {
      short4v af = pack_bf16x4(s[kc][0], s[kc][1], s[kc][2], s[kc][3]);
#pragma unroll
      for (int nd = 0; nd < 4; nd++) {
        uint2 vv = *(const uint2*)&Vb[(kc * 4 + g) * 264 + (nd * 16 + c) * 4];
        short4v vf = __builtin_bit_cast(short4v, vv);
        oa[nd] = __builtin_amdgcn_mfma_f32_16x16x16bf16_1k(af, vf, oa[nd], 0, 0, 0);
      }
    }
  };

  int p = 0;
  for (int jt = 0; jt <= jmaxB; jt++) {
    // store prefetched tile into buf[p] (consumers of buf[p] finished 2 iters ago,
    // ordered by last iteration's barrier)
    *(uint4*)&Ks[p][(e0 >> 5) * 40 + (e0 & 31)] = kr0;
    *(uint4*)&Ks[p][(e1 >> 5) * 40 + (e1 & 31)] = kr1;
#pragma unroll
    for (int q = 0; q < 4; q++) {
      int e = (q * 256 + tid) * 8;
      *(uint4*)&Vs[p][(e >> 8) * 264 + (e & 255)] = vr[q];
    }
    __syncthreads();
    if (jt < jmaxB) {                    // prefetch next tile; flies under compute
      const unsigned short* kp = &klr[kbase + (size_t)(jt + 1) * 128 * 32];
      kr0 = *(const uint4*)&kp[e0];
      kr1 = *(const uint4*)&kp[e1];
      const unsigned short* vp = &vt[vbase + (size_t)(jt + 1) * 8192];
#pragma unroll
      for (int q = 0; q < 4; q++)
        vr[q] = *(const uint4*)&vp[(q * 256 + tid) * 8];
    }
    compute_tile(qfB, oaB, miB, liB, qgB, jt == jmaxB, jt, p);
    if (jt <= jmaxA) compute_tile(qfA, oaA, miA, liA, qgA, jt == jmaxA, jt, p);
    p ^= 1;
  }

  // epilogue: O already in natural orientation; fold 1/li (per-q broadcast) and store
#pragma unroll
  for (int phase = 0; phase < 2; phase++) {
    const f32x4* oa = phase ? oaA : oaB;
    float inv = 1.f / (phase ? liA : liB);   // q=c
    int q0 = phase ? q0A : q0B;
    float iv[4];
#pragma unroll
    for (int r = 0; r < 4; r++) iv[r] = __shfl(inv, srcl + r, 64);
#pragma unroll
    for (int r = 0; r < 4; r++) {
      size_t rowb = ((size_t)b * TT + q0 + w * 16 + g * 4 + r) * DD + h * 64;
#pragma unroll
      for (int nd = 0; nd < 4; nd++)
        attn[rowb + nd * 16 + c] = f2bf(oa[nd][r] * iv[r]);
    }
  }
}

extern "C" void kernel_launch(void* const* d_in, const int* in_sizes, int n_in,
                              void* d_out, int out_size, void* d_ws, size_t ws_size,
                              hipStream_t stream) {
  const float* x      = (const float*)d_in[0];  // (B,T,1024) fp32
  const float* W_qkv  = (const float*)d_in[1];  // (1024,3072) fp32
  const float* W_qlsr = (const float*)d_in[2];  // (16,64,16)  fp32
  const float* W_klsr = (const float*)d_in[3];  // (16,64,16)  fp32
  const float* core   = (const float*)d_in[4];  // (16,16)     fp32
  const float* W_o    = (const float*)d_in[5];  // (1024,1024) fp32
  float* out = (float*)d_out;                   // (B,T,1024)  fp32

  char* ws = (char*)d_ws;
  unsigned short* x_bf   = (unsigned short*)ws; ws += (size_t)BT * DD * 2;   // (4096,1024)
  unsigned short* Wqkv_t = (unsigned short*)ws; ws += (size_t)D3 * DD * 2;   // (3072,1024)
  unsigned short* Wo_t   = (unsigned short*)ws; ws += (size_t)DD * DD * 2;   // (1024,1024)
  unsigned short* qkv    = (unsigned short*)ws; ws += (size_t)BT * D3 * 2;   // (4096,3072)
  unsigned short* qls    = (unsigned short*)ws; ws += (size_t)BH * TT * 32 * 2;
  unsigned short* klr    = (unsigned short*)ws; ws += (size_t)BH * TT * 32 * 2;
  unsigned short* vt     = (unsigned short*)ws; ws += (size_t)BH * (TT / 4) * 256 * 2;
  unsigned short* attn   = (unsigned short*)ws; ws += (size_t)BT * DD * 2;

  cvt_f32_bf16<<<(BT * DD) / (256 * 8), 256, 0, stream>>>(x, x_bf, BT * DD);
  transpose_cvt<<<dim3(D3 / 32, DD / 32), dim3(32, 8), 0, stream>>>(W_qkv, Wqkv_t, DD, D3);
  transpose_cvt<<<dim3(DD / 32, DD / 32), dim3(32, 8), 0, stream>>>(W_o, Wo_t, DD, DD);
  gemm_bt<false><<<dim3(D3 / 128, BT / 128), 256, 0, stream>>>(x_bf, Wqkv_t, qkv, BT, D3, DD);
  lsr_repack<<<dim3(TT / 64, BH), 256, 0, stream>>>(qkv, W_qlsr, W_klsr, core, qls, klr, vt);
  flash_lsr<<<dim3(16, BH), 256, 0, stream>>>(qls, klr, vt, attn);
  gemm_bt<true><<<dim3(DD / 128, BT / 128), 256, 0, stream>>>(attn, Wo_t, out, BT, DD, DD);
}

// Round 8
// 243.268 us; speedup vs baseline: 1.3122x; 1.0639x over previous
//
#include <hip/hip_runtime.h>
#include <hip/hip_bf16.h>

// Problem constants
#define BB 2
#define TT 2048
#define DD 1024
#define HH 16
#define DH 64
#define RR 16
#define BT (BB*TT)      // 4096
#define BH (BB*HH)      // 32
#define D3 (3*DD)       // 3072
#define NC 1536         // fused GEMM1 N: 1024 V + 256 q_lr + 256 k_lr

typedef __bf16 bf16x8 __attribute__((ext_vector_type(8)));
typedef float f32x4 __attribute__((ext_vector_type(4)));
typedef short short4v __attribute__((ext_vector_type(4)));

__device__ __forceinline__ float bf2f(unsigned short u) {
  unsigned int v = ((unsigned int)u) << 16;
  return __builtin_bit_cast(float, v);
}
__device__ __forceinline__ unsigned short f2bf(float f) {
  unsigned int x = __builtin_bit_cast(unsigned int, f);
  unsigned int r = x + 0x7fffu + ((x >> 16) & 1u);
  return (unsigned short)(r >> 16);
}
__device__ __forceinline__ short4v pack_bf16x4(float a, float b, float c, float d) {
  uint2 u;
  u.x = (unsigned)f2bf(a) | ((unsigned)f2bf(b) << 16);
  u.y = (unsigned)f2bf(c) | ((unsigned)f2bf(d) << 16);
  return __builtin_bit_cast(short4v, u);
}

#define NEG_BIG (-1e30f)

__device__ __forceinline__ void async_copy16(const void* g, void* l) {
  __builtin_amdgcn_global_load_lds((const __attribute__((address_space(1))) void*)g,
                                   (__attribute__((address_space(3))) void*)l, 16, 0, 0);
}

// ---------------- fp32 -> bf16 elementwise convert ---------------------------------
__global__ __launch_bounds__(256) void cvt_f32_bf16(const float* __restrict__ in,
                                                    unsigned short* __restrict__ out,
                                                    int n) {
  int i = (blockIdx.x * 256 + threadIdx.x) * 8;
  if (i >= n) return;
  float4 a = *(const float4*)&in[i];
  float4 b = *(const float4*)&in[i + 4];
  unsigned short t[8] = {f2bf(a.x), f2bf(a.y), f2bf(a.z), f2bf(a.w),
                         f2bf(b.x), f2bf(b.y), f2bf(b.z), f2bf(b.w)};
  *(uint4*)&out[i] = *(const uint4*)t;
}

// ---------------- transpose+cvt: out[j][d] = in[d][coff+j], fp32->bf16 --------------
__global__ __launch_bounds__(256) void transpose_cvt(const float* __restrict__ in,
                                                     unsigned short* __restrict__ out,
                                                     int R, int C, int coff) {
  __shared__ float tile[32][33];
  const int tx = threadIdx.x, ty = threadIdx.y;
  const int x = blockIdx.x * 32 + tx;
  const int y0 = blockIdx.y * 32;
#pragma unroll
  for (int i = 0; i < 32; i += 8)
    tile[ty + i][tx] = in[(size_t)(y0 + ty + i) * C + coff + x];
  __syncthreads();
  const int xo = y0 + tx;
  const int yo0 = blockIdx.x * 32;
#pragma unroll
  for (int i = 0; i < 32; i += 8)
    out[(size_t)(yo0 + ty + i) * R + xo] = f2bf(tile[tx][ty + i]);
}

// ---------------- combined LSR weights: Wcomb rows 1024..1535 ----------------------
// Wcomb_t[1024+h*16+r][d] = 0.25*core[h,r] * sum_e W_qkv[d][h*64+e]*W_qlsr[h,e,r]
// Wcomb_t[1280+h*16+r][d] =                  sum_e W_qkv[d][1024+h*64+e]*W_klsr[h,e,r]
__global__ __launch_bounds__(256) void build_lsr(const float* __restrict__ Wqkv,
                                                 const float* __restrict__ Wql,
                                                 const float* __restrict__ Wkl,
                                                 const float* __restrict__ core,
                                                 unsigned short* __restrict__ Wcomb_t) {
  const int d0 = blockIdx.x * 64, h = blockIdx.y, tid = threadIdx.x;
  __shared__ float Aq[64][65], Ak[64][65], Lq[64][16], Lk[64][16], cs[16];
#pragma unroll
  for (int p = 0; p < 16; p++) {
    int idx = p * 256 + tid, dd = idx >> 6, e = idx & 63;
    Aq[dd][e] = Wqkv[(size_t)(d0 + dd) * D3 + h * 64 + e];
    Ak[dd][e] = Wqkv[(size_t)(d0 + dd) * D3 + DD + h * 64 + e];
  }
#pragma unroll
  for (int p = 0; p < 4; p++) {
    int idx = p * 256 + tid, e = idx >> 4, r = idx & 15;
    Lq[e][r] = Wql[h * 1024 + e * 16 + r];
    Lk[e][r] = Wkl[h * 1024 + e * 16 + r];
  }
  if (tid < 16) cs[tid] = core[h * 16 + tid];
  __syncthreads();
  const int dd = tid & 63, rg = tid >> 6;
  float aq[4] = {}, ak[4] = {};
  for (int e = 0; e < 64; e++) {
    float xq = Aq[dd][e], xk = Ak[dd][e];
#pragma unroll
    for (int j = 0; j < 4; j++) {
      aq[j] += xq * Lq[e][rg * 4 + j];
      ak[j] += xk * Lk[e][rg * 4 + j];
    }
  }
#pragma unroll
  for (int j = 0; j < 4; j++) {
    int r = rg * 4 + j;
    Wcomb_t[(size_t)(1024 + h * 16 + r) * DD + d0 + dd] = f2bf(aq[j] * cs[r] * 0.25f);
    Wcomb_t[(size_t)(1280 + h * 16 + r) * DD + d0 + dd] = f2bf(ak[j]);
  }
}

// ---------------- bf16 GEMM core: 64x128 tile, BK=32, 4 waves 2x2, acc[2][4] --------
// A row-major (Mx K), Bt row-major (N x K). Wave (wm,wn) computes rows wm*32+,
// cols wn*64+. Returns accumulators in acc.
__device__ __forceinline__ void gemm64_core(const unsigned short* __restrict__ A,
                                            const unsigned short* __restrict__ Bt,
                                            int K, int bm, int bn,
                                            int tid, int g, int c, int wm, int wn,
                                            f32x4 acc[2][4]) {
  __shared__ __attribute__((aligned(16))) unsigned short As[64 * 32];
  __shared__ __attribute__((aligned(16))) unsigned short Bs[128 * 32];
  const int e0 = tid * 8;
  const int r0 = e0 >> 5, q0 = e0 & 31;
  const unsigned short* Arow = &A[(size_t)(bm * 64 + r0) * K + q0];
  const unsigned short* Brow0 = &Bt[(size_t)(bn * 128 + r0) * K + q0];
  const unsigned short* Brow1 = &Bt[(size_t)(bn * 128 + 64 + r0) * K + q0];
  for (int k0 = 0; k0 < K; k0 += 32) {
    __syncthreads();
    async_copy16(Arow + k0, &As[e0]);
    async_copy16(Brow0 + k0, &Bs[e0]);
    async_copy16(Brow1 + k0, &Bs[2048 + e0]);
    __syncthreads();
    bf16x8 af[2];
#pragma unroll
    for (int mt = 0; mt < 2; mt++)
      af[mt] = *(const bf16x8*)&As[(wm * 32 + mt * 16 + c) * 32 + g * 8];
#pragma unroll
    for (int nt = 0; nt < 4; nt++) {
      bf16x8 bf = *(const bf16x8*)&Bs[(wn * 64 + nt * 16 + c) * 32 + g * 8];
#pragma unroll
      for (int mt = 0; mt < 2; mt++)
        acc[mt][nt] = __builtin_amdgcn_mfma_f32_16x16x32_bf16(af[mt], bf, acc[mt][nt], 0, 0, 0);
    }
  }
}

// gemm2: C fp32 row-major
__global__ __launch_bounds__(256) void gemm64_f32(const unsigned short* __restrict__ A,
                                                  const unsigned short* __restrict__ Bt,
                                                  float* __restrict__ C,
                                                  int M, int N, int K) {
  const int tid = threadIdx.x, lane = tid & 63;
  const int g = lane >> 4, c = lane & 15;
  const int wid = tid >> 6, wm = wid >> 1, wn = wid & 1;
  const int bm = blockIdx.y, bn = blockIdx.x;
  f32x4 acc[2][4] = {};
  gemm64_core(A, Bt, K, bm, bn, tid, g, c, wm, wn, acc);
#pragma unroll
  for (int mt = 0; mt < 2; mt++)
#pragma unroll
    for (int nt = 0; nt < 4; nt++)
#pragma unroll
      for (int r = 0; r < 4; r++) {
        int row = bm * 64 + wm * 32 + mt * 16 + g * 4 + r;
        int col = bn * 128 + wn * 64 + nt * 16 + c;
        C[(size_t)row * N + col] = acc[mt][nt][r];
      }
}

// gemm1 fused: A = x_bf (4096x1024), Bt = Wcomb_t (1536x1024).
// Epilogue scatters: cols<1024 -> vt swizzled (BH,T/4,64,4); 1024..1279 -> qls; >=1280 -> klr.
__global__ __launch_bounds__(256) void gemm_fused(const unsigned short* __restrict__ A,
                                                  const unsigned short* __restrict__ Bt,
                                                  unsigned short* __restrict__ qls,
                                                  unsigned short* __restrict__ klr,
                                                  unsigned short* __restrict__ vt,
                                                  int M, int N, int K) {
  const int tid = threadIdx.x, lane = tid & 63;
  const int g = lane >> 4, c = lane & 15;
  const int wid = tid >> 6, wm = wid >> 1, wn = wid & 1;
  const int bm = blockIdx.y, bn = blockIdx.x;
  f32x4 acc[2][4] = {};
  gemm64_core(A, Bt, K, bm, bn, tid, g, c, wm, wn, acc);
#pragma unroll
  for (int mt = 0; mt < 2; mt++)
#pragma unroll
    for (int nt = 0; nt < 4; nt++) {
      int colb = bn * 128 + wn * 64 + nt * 16;        // + c
      int tg0 = bm * 64 + wm * 32 + mt * 16 + g * 4;  // tokens tg0..tg0+3 (4-aligned)
      int b = tg0 >> 11, t0 = tg0 & 2047;
      if (colb < 1024) {
        int h = colb >> 6, d = (colb & 63) + c;
        // t0..t0+3 share t>>2; t&3 == r -> 4 bf16 contiguous = one 8B store
        uint2 pk = __builtin_bit_cast(uint2, pack_bf16x4(acc[mt][nt][0], acc[mt][nt][1],
                                                         acc[mt][nt][2], acc[mt][nt][3]));
        size_t idx = (size_t)(b * 16 + h) * (TT / 4) * 256 + (size_t)(t0 >> 2) * 256 + d * 4;
        *(uint2*)&vt[idx] = pk;
      } else if (colb < 1280) {
        int h = (colb - 1024) >> 4;
        size_t base = (size_t)(b * 16 + h) * TT;
#pragma unroll
        for (int r = 0; r < 4; r++)
          qls[(base + t0 + r) * 16 + c] = f2bf(acc[mt][nt][r]);
      } else {
        int h = (colb - 1280) >> 4;
        size_t base = (size_t)(b * 16 + h) * TT;
#pragma unroll
        for (int r = 0; r < 4; r++)
          klr[(base + t0 + r) * 16 + c] = f2bf(acc[mt][nt][r]);
      }
    }
}

// ---------------- Flash attention v5: K direct from L2, V-only LDS, K=16 MFMAs ------
// grid (32, BH), 256 thr = 4 waves; it = 31-bx (heavy-first). Wave w owns q-cols
// [w*16, w*16+16) of the 64-row tile. S^T via K=16 MFMA (R=16, no padding); PV
// consumes softmaxed scores directly from registers (A-layout match, zero transform).
__global__ __launch_bounds__(256, 4) void flash_lsr(const unsigned short* __restrict__ qls,
                                                    const unsigned short* __restrict__ klr,
                                                    const unsigned short* __restrict__ vt,
                                                    unsigned short* __restrict__ attn) {
  const int it = 31 - blockIdx.x;
  const int bh = blockIdx.y, b = bh >> 4, h = bh & 15;
  const int tid = threadIdx.x, lane = tid & 63, w = tid >> 6;
  const int g = lane >> 4, c = lane & 15;
  const int q0 = it * 64;
  const int jmax = it >> 1;

  __shared__ __attribute__((aligned(16))) unsigned short Vs[32 * 264];  // 16.5 KB

  short4v qf = __builtin_bit_cast(short4v,
      *(const uint2*)&qls[((size_t)bh * TT + q0 + w * 16 + c) * 16 + g * 4]);
  const int qg = q0 + w * 16 + c;
  float mi = NEG_BIG, li = 0.f;
  f32x4 oa[4] = {};
  const f32x4 zero = {0.f, 0.f, 0.f, 0.f};
  const size_t kb = (size_t)bh * TT * 16;
  const size_t vb = (size_t)bh * TT * 64;
  const int srcl = g * 16 + g * 4;

  uint4 vr[4];
#pragma unroll
  for (int p = 0; p < 4; p++)
    vr[p] = *(const uint4*)&vt[vb + (p * 256 + tid) * 8];

  for (int jt = 0; jt <= jmax; jt++) {
    __syncthreads();                     // prev-iter Vs consumers done
#pragma unroll
    for (int p = 0; p < 4; p++) {
      int e = (p * 256 + tid) * 8;
      *(uint4*)&Vs[(e >> 8) * 264 + (e & 255)] = vr[p];
    }
    __syncthreads();
    if (jt < jmax) {
      const unsigned short* vp = &vt[vb + (size_t)(jt + 1) * 8192];
#pragma unroll
      for (int p = 0; p < 4; p++)
        vr[p] = *(const uint4*)&vp[(p * 256 + tid) * 8];
    }

    // S^T: K fragments straight from global (L2-resident, coalesced per nt-strip)
    const unsigned short* kt = &klr[kb + (size_t)jt * 2048];
    f32x4 s[8];
#pragma unroll
    for (int nt = 0; nt < 8; nt++) {
      short4v kf = __builtin_bit_cast(short4v, *(const uint2*)&kt[(nt * 16 + c) * 16 + g * 4]);
      s[nt] = __builtin_amdgcn_mfma_f32_16x16x16bf16_1k(kf, qf, zero, 0, 0, 0);
    }
    if (jt == jmax) {
#pragma unroll
      for (int nt = 0; nt < 8; nt++)
#pragma unroll
        for (int r = 0; r < 4; r++) {
          int jg = jt * 128 + nt * 16 + g * 4 + r;
          if (jg > qg) s[nt][r] = NEG_BIG;
        }
    }
    // per-lane: 32 scores all for q=c; reduce across the 4 c-sharing lanes
    f32x4 vm = s[0];
#pragma unroll
    for (int nt = 1; nt < 8; nt++)
#pragma unroll
      for (int r = 0; r < 4; r++) vm[r] = fmaxf(vm[r], s[nt][r]);
    float rm = fmaxf(fmaxf(vm[0], vm[1]), fmaxf(vm[2], vm[3]));
    rm = fmaxf(rm, __shfl_xor(rm, 16, 64));
    rm = fmaxf(rm, __shfl_xor(rm, 32, 64));
    float mnew = fmaxf(mi, rm);
    float alpha = __expf(mi - mnew);
    mi = mnew;
    f32x4 vs = zero;
#pragma unroll
    for (int nt = 0; nt < 8; nt++)
#pragma unroll
      for (int r = 0; r < 4; r++) {
        float pv = __expf(s[nt][r] - mnew);
        s[nt][r] = pv;
        vs[r] += pv;
      }
    float rs = (vs[0] + vs[1]) + (vs[2] + vs[3]);
    rs += __shfl_xor(rs, 16, 64);
    rs += __shfl_xor(rs, 32, 64);
    li = li * alpha + rs;
    float av[4];
#pragma unroll
    for (int r = 0; r < 4; r++) av[r] = __shfl(alpha, srcl + r, 64);
#pragma unroll
    for (int nd = 0; nd < 4; nd++)
#pragma unroll
      for (int r = 0; r < 4; r++) oa[nd][r] *= av[r];
    // PV: O[q][d] += P*V via K=16 MFMAs; A-frag = packed scores (zero transform)
#pragma unroll
    for (int kc = 0; kc < 8; kc++) {
      short4v af = pack_bf16x4(s[kc][0], s[kc][1], s[kc][2], s[kc][3]);
#pragma unroll
      for (int nd = 0; nd < 4; nd++) {
        uint2 vv = *(const uint2*)&Vs[(kc * 4 + g) * 264 + (nd * 16 + c) * 4];
        short4v vf = __builtin_bit_cast(short4v, vv);
        oa[nd] = __builtin_amdgcn_mfma_f32_16x16x16bf16_1k(af, vf, oa[nd], 0, 0, 0);
      }
    }
  }

  // epilogue: O in natural orientation; fold 1/li (per-q broadcast) and store
  float inv = 1.f / li;                  // per q=c
  float iv[4];
#pragma unroll
  for (int r = 0; r < 4; r++) iv[r] = __shfl(inv, srcl + r, 64);
#pragma unroll
  for (int r = 0; r < 4; r++) {
    size_t rowb = ((size_t)b * TT + q0 + w * 16 + g * 4 + r) * DD + h * 64;
#pragma unroll
    for (int nd = 0; nd < 4; nd++)
      attn[rowb + nd * 16 + c] = f2bf(oa[nd][r] * iv[r]);
  }
}

extern "C" void kernel_launch(void* const* d_in, const int* in_sizes, int n_in,
                              void* d_out, int out_size, void* d_ws, size_t ws_size,
                              hipStream_t stream) {
  const float* x      = (const float*)d_in[0];  // (B,T,1024) fp32
  const float* W_qkv  = (const float*)d_in[1];  // (1024,3072) fp32
  const float* W_qlsr = (const float*)d_in[2];  // (16,64,16)  fp32
  const float* W_klsr = (const float*)d_in[3];  // (16,64,16)  fp32
  const float* core   = (const float*)d_in[4];  // (16,16)     fp32
  const float* W_o    = (const float*)d_in[5];  // (1024,1024) fp32
  float* out = (float*)d_out;                   // (B,T,1024)  fp32

  char* ws = (char*)d_ws;
  unsigned short* x_bf    = (unsigned short*)ws; ws += (size_t)BT * DD * 2;
  unsigned short* Wcomb_t = (unsigned short*)ws; ws += (size_t)NC * DD * 2;
  unsigned short* Wo_t    = (unsigned short*)ws; ws += (size_t)DD * DD * 2;
  unsigned short* qls     = (unsigned short*)ws; ws += (size_t)BH * TT * 16 * 2;
  unsigned short* klr     = (unsigned short*)ws; ws += (size_t)BH * TT * 16 * 2;
  unsigned short* vt      = (unsigned short*)ws; ws += (size_t)BH * TT * 64 * 2;
  unsigned short* attn    = (unsigned short*)ws; ws += (size_t)BT * DD * 2;

  cvt_f32_bf16<<<(BT * DD) / (256 * 8), 256, 0, stream>>>(x, x_bf, BT * DD);
  transpose_cvt<<<dim3(32, 32), dim3(32, 8), 0, stream>>>(W_o, Wo_t, DD, DD, 0);
  // Wcomb rows 0..1023: transpose of W_qkv V-columns
  transpose_cvt<<<dim3(32, 32), dim3(32, 8), 0, stream>>>(W_qkv, Wcomb_t, DD, D3, 2048);
  build_lsr<<<dim3(16, 16), 256, 0, stream>>>(W_qkv, W_qlsr, W_klsr, core, Wcomb_t);
  gemm_fused<<<dim3(NC / 128, BT / 64), 256, 0, stream>>>(x_bf, Wcomb_t, qls, klr, vt, BT, NC, DD);
  flash_lsr<<<dim3(32, BH), 256, 0, stream>>>(qls, klr, vt, attn);
  gemm64_f32<<<dim3(DD / 128, BT / 64), 256, 0, stream>>>(attn, Wo_t, out, BT, DD, DD);
}

// Round 9
// 198.780 us; speedup vs baseline: 1.6059x; 1.2238x over previous
//
#include <hip/hip_runtime.h>
#include <hip/hip_bf16.h>

// Problem constants
#define BB 2
#define TT 2048
#define DD 1024
#define HH 16
#define DH 64
#define RR 16
#define BT (BB*TT)      // 4096
#define BH (BB*HH)      // 32
#define D3 (3*DD)       // 3072
#define NC 1536         // fused GEMM1 N: 1024 V + 256 q_lr + 256 k_lr

typedef __bf16 bf16x8 __attribute__((ext_vector_type(8)));
typedef float f32x4 __attribute__((ext_vector_type(4)));
typedef short short4v __attribute__((ext_vector_type(4)));

__device__ __forceinline__ float bf2f(unsigned short u) {
  unsigned int v = ((unsigned int)u) << 16;
  return __builtin_bit_cast(float, v);
}
__device__ __forceinline__ unsigned short f2bf(float f) {
  unsigned int x = __builtin_bit_cast(unsigned int, f);
  unsigned int r = x + 0x7fffu + ((x >> 16) & 1u);
  return (unsigned short)(r >> 16);
}
__device__ __forceinline__ short4v pack_bf16x4(float a, float b, float c, float d) {
  uint2 u;
  u.x = (unsigned)f2bf(a) | ((unsigned)f2bf(b) << 16);
  u.y = (unsigned)f2bf(c) | ((unsigned)f2bf(d) << 16);
  return __builtin_bit_cast(short4v, u);
}

#define NEG_BIG (-1e30f)

__device__ __forceinline__ void async_copy16(const void* g, void* l) {
  __builtin_amdgcn_global_load_lds((const __attribute__((address_space(1))) void*)g,
                                   (__attribute__((address_space(3))) void*)l, 16, 0, 0);
}

// ---------------- fp32 -> bf16 elementwise convert ---------------------------------
__global__ __launch_bounds__(256) void cvt_f32_bf16(const float* __restrict__ in,
                                                    unsigned short* __restrict__ out,
                                                    int n) {
  int i = (blockIdx.x * 256 + threadIdx.x) * 8;
  if (i >= n) return;
  float4 a = *(const float4*)&in[i];
  float4 b = *(const float4*)&in[i + 4];
  unsigned short t[8] = {f2bf(a.x), f2bf(a.y), f2bf(a.z), f2bf(a.w),
                         f2bf(b.x), f2bf(b.y), f2bf(b.z), f2bf(b.w)};
  *(uint4*)&out[i] = *(const uint4*)t;
}

// ---------------- transpose+cvt: out[j][d] = in[d][coff+j], fp32->bf16 --------------
__global__ __launch_bounds__(256) void transpose_cvt(const float* __restrict__ in,
                                                     unsigned short* __restrict__ out,
                                                     int R, int C, int coff) {
  __shared__ float tile[32][33];
  const int tx = threadIdx.x, ty = threadIdx.y;
  const int x = blockIdx.x * 32 + tx;
  const int y0 = blockIdx.y * 32;
#pragma unroll
  for (int i = 0; i < 32; i += 8)
    tile[ty + i][tx] = in[(size_t)(y0 + ty + i) * C + coff + x];
  __syncthreads();
  const int xo = y0 + tx;
  const int yo0 = blockIdx.x * 32;
#pragma unroll
  for (int i = 0; i < 32; i += 8)
    out[(size_t)(yo0 + ty + i) * R + xo] = f2bf(tile[tx][ty + i]);
}

// ---------------- combined LSR weights: Wcomb rows 1024..1535 ----------------------
__global__ __launch_bounds__(256) void build_lsr(const float* __restrict__ Wqkv,
                                                 const float* __restrict__ Wql,
                                                 const float* __restrict__ Wkl,
                                                 const float* __restrict__ core,
                                                 unsigned short* __restrict__ Wcomb_t) {
  const int d0 = blockIdx.x * 64, h = blockIdx.y, tid = threadIdx.x;
  __shared__ float Aq[64][65], Ak[64][65], Lq[64][16], Lk[64][16], cs[16];
#pragma unroll
  for (int p = 0; p < 16; p++) {
    int idx = p * 256 + tid, dd = idx >> 6, e = idx & 63;
    Aq[dd][e] = Wqkv[(size_t)(d0 + dd) * D3 + h * 64 + e];
    Ak[dd][e] = Wqkv[(size_t)(d0 + dd) * D3 + DD + h * 64 + e];
  }
#pragma unroll
  for (int p = 0; p < 4; p++) {
    int idx = p * 256 + tid, e = idx >> 4, r = idx & 15;
    Lq[e][r] = Wql[h * 1024 + e * 16 + r];
    Lk[e][r] = Wkl[h * 1024 + e * 16 + r];
  }
  if (tid < 16) cs[tid] = core[h * 16 + tid];
  __syncthreads();
  const int dd = tid & 63, rg = tid >> 6;
  float aq[4] = {}, ak[4] = {};
  for (int e = 0; e < 64; e++) {
    float xq = Aq[dd][e], xk = Ak[dd][e];
#pragma unroll
    for (int j = 0; j < 4; j++) {
      aq[j] += xq * Lq[e][rg * 4 + j];
      ak[j] += xk * Lk[e][rg * 4 + j];
    }
  }
#pragma unroll
  for (int j = 0; j < 4; j++) {
    int r = rg * 4 + j;
    Wcomb_t[(size_t)(1024 + h * 16 + r) * DD + d0 + dd] = f2bf(aq[j] * cs[r] * 0.25f);
    Wcomb_t[(size_t)(1280 + h * 16 + r) * DD + d0 + dd] = f2bf(ak[j]);
  }
}

// ---------------- bf16 GEMM core: 64x128 tile, BK=32, 4 waves 2x2, acc[2][4] --------
__device__ __forceinline__ void gemm64_core(const unsigned short* __restrict__ A,
                                            const unsigned short* __restrict__ Bt,
                                            int K, int bm, int bn,
                                            int tid, int g, int c, int wm, int wn,
                                            f32x4 acc[2][4]) {
  __shared__ __attribute__((aligned(16))) unsigned short As[64 * 32];
  __shared__ __attribute__((aligned(16))) unsigned short Bs[128 * 32];
  const int e0 = tid * 8;
  const int r0 = e0 >> 5, q0 = e0 & 31;
  const unsigned short* Arow = &A[(size_t)(bm * 64 + r0) * K + q0];
  const unsigned short* Brow0 = &Bt[(size_t)(bn * 128 + r0) * K + q0];
  const unsigned short* Brow1 = &Bt[(size_t)(bn * 128 + 64 + r0) * K + q0];
  for (int k0 = 0; k0 < K; k0 += 32) {
    __syncthreads();
    async_copy16(Arow + k0, &As[e0]);
    async_copy16(Brow0 + k0, &Bs[e0]);
    async_copy16(Brow1 + k0, &Bs[2048 + e0]);
    __syncthreads();
    bf16x8 af[2];
#pragma unroll
    for (int mt = 0; mt < 2; mt++)
      af[mt] = *(const bf16x8*)&As[(wm * 32 + mt * 16 + c) * 32 + g * 8];
#pragma unroll
    for (int nt = 0; nt < 4; nt++) {
      bf16x8 bf = *(const bf16x8*)&Bs[(wn * 64 + nt * 16 + c) * 32 + g * 8];
#pragma unroll
      for (int mt = 0; mt < 2; mt++)
        acc[mt][nt] = __builtin_amdgcn_mfma_f32_16x16x32_bf16(af[mt], bf, acc[mt][nt], 0, 0, 0);
    }
  }
}

// gemm2: C fp32 row-major
__global__ __launch_bounds__(256) void gemm64_f32(const unsigned short* __restrict__ A,
                                                  const unsigned short* __restrict__ Bt,
                                                  float* __restrict__ C,
                                                  int M, int N, int K) {
  const int tid = threadIdx.x, lane = tid & 63;
  const int g = lane >> 4, c = lane & 15;
  const int wid = tid >> 6, wm = wid >> 1, wn = wid & 1;
  const int bm = blockIdx.y, bn = blockIdx.x;
  f32x4 acc[2][4] = {};
  gemm64_core(A, Bt, K, bm, bn, tid, g, c, wm, wn, acc);
#pragma unroll
  for (int mt = 0; mt < 2; mt++)
#pragma unroll
    for (int nt = 0; nt < 4; nt++)
#pragma unroll
      for (int r = 0; r < 4; r++) {
        int row = bm * 64 + wm * 32 + mt * 16 + g * 4 + r;
        int col = bn * 128 + wn * 64 + nt * 16 + c;
        C[(size_t)row * N + col] = acc[mt][nt][r];
      }
}

// gemm1 fused: A = x_bf (4096x1024), Bt = Wcomb_t (1536x1024).
__global__ __launch_bounds__(256) void gemm_fused(const unsigned short* __restrict__ A,
                                                  const unsigned short* __restrict__ Bt,
                                                  unsigned short* __restrict__ qls,
                                                  unsigned short* __restrict__ klr,
                                                  unsigned short* __restrict__ vt,
                                                  int M, int N, int K) {
  const int tid = threadIdx.x, lane = tid & 63;
  const int g = lane >> 4, c = lane & 15;
  const int wid = tid >> 6, wm = wid >> 1, wn = wid & 1;
  const int bm = blockIdx.y, bn = blockIdx.x;
  f32x4 acc[2][4] = {};
  gemm64_core(A, Bt, K, bm, bn, tid, g, c, wm, wn, acc);
#pragma unroll
  for (int mt = 0; mt < 2; mt++)
#pragma unroll
    for (int nt = 0; nt < 4; nt++) {
      int colb = bn * 128 + wn * 64 + nt * 16;        // + c
      int tg0 = bm * 64 + wm * 32 + mt * 16 + g * 4;  // tokens tg0..tg0+3 (4-aligned)
      int b = tg0 >> 11, t0 = tg0 & 2047;
      if (colb < 1024) {
        int h = colb >> 6, d = (colb & 63) + c;
        uint2 pk = __builtin_bit_cast(uint2, pack_bf16x4(acc[mt][nt][0], acc[mt][nt][1],
                                                         acc[mt][nt][2], acc[mt][nt][3]));
        size_t idx = (size_t)(b * 16 + h) * (TT / 4) * 256 + (size_t)(t0 >> 2) * 256 + d * 4;
        *(uint2*)&vt[idx] = pk;
      } else if (colb < 1280) {
        int h = (colb - 1024) >> 4;
        size_t base = (size_t)(b * 16 + h) * TT;
#pragma unroll
        for (int r = 0; r < 4; r++)
          qls[(base + t0 + r) * 16 + c] = f2bf(acc[mt][nt][r]);
      } else {
        int h = (colb - 1280) >> 4;
        size_t base = (size_t)(b * 16 + h) * TT;
#pragma unroll
        for (int r = 0; r < 4; r++)
          klr[(base + t0 + r) * 16 + c] = f2bf(acc[mt][nt][r]);
      }
    }
}

// ---------------- Flash attention v6: paired tiles + dbuf K/V LDS + K=16 MFMAs ------
// grid (16, BH), 256 thr = 4 waves. Block z handles 64-row Q-tiles z and 31-z in ONE
// j-loop (uniform 17 tile-computes). K AND V staged in double-buffered LDS via
// register prefetch (loads fly under the 2 tile-computes); ONE barrier per j-iter.
// S^T via K=16 MFMA; PV consumes softmaxed scores directly from registers.
__global__ __launch_bounds__(256) void flash_lsr(const unsigned short* __restrict__ qls,
                                                 const unsigned short* __restrict__ klr,
                                                 const unsigned short* __restrict__ vt,
                                                 unsigned short* __restrict__ attn) {
  const int z = blockIdx.x;             // 0..15
  const int bh = blockIdx.y, b = bh >> 4, h = bh & 15;
  const int tid = threadIdx.x, lane = tid & 63, w = tid >> 6;
  const int g = lane >> 4, c = lane & 15;
  const int q0A = z * 64, q0B = (31 - z) * 64;
  const int jmaxA = z >> 1, jmaxB = (31 - z) >> 1;

  __shared__ __attribute__((aligned(16))) unsigned short Ks[2][128 * 20];  // 2x5.0 KB (20-el rows: conflict-free b64)
  __shared__ __attribute__((aligned(16))) unsigned short Vs[2][32 * 264];  // 2x16.5 KB (conflict-free, measured R8)

  const size_t qbase = (size_t)bh * TT;
  short4v qfA = __builtin_bit_cast(short4v,
      *(const uint2*)&qls[(qbase + q0A + w * 16 + c) * 16 + g * 4]);
  short4v qfB = __builtin_bit_cast(short4v,
      *(const uint2*)&qls[(qbase + q0B + w * 16 + c) * 16 + g * 4]);
  const int qgA = q0A + w * 16 + c, qgB = q0B + w * 16 + c;
  float miA = NEG_BIG, liA = 0.f, miB = NEG_BIG, liB = 0.f;
  f32x4 oaA[4] = {}, oaB[4] = {};
  const f32x4 zero = {0.f, 0.f, 0.f, 0.f};
  const size_t kb = (size_t)bh * TT * 16;
  const size_t vb = (size_t)bh * TT * 64;
  const int srcl = g * 16 + g * 4;

  // prefetch j-tile 0 into registers
  uint4 kr = *(const uint4*)&klr[kb + tid * 8];
  uint4 vr[4];
#pragma unroll
  for (int p = 0; p < 4; p++)
    vr[p] = *(const uint4*)&vt[vb + (p * 256 + tid) * 8];

  // one Q-tile's update against the staged j-tile (buffer pb)
  auto compute_tile = [&](const short4v& qf, f32x4* oa, float& mi, float& li,
                          int qg, bool diag, int jt, int pb) {
    const unsigned short* Kb = Ks[pb];
    const unsigned short* Vb = Vs[pb];
    f32x4 s[8];
#pragma unroll
    for (int nt = 0; nt < 8; nt++) {
      short4v kf = __builtin_bit_cast(short4v, *(const uint2*)&Kb[(nt * 16 + c) * 20 + g * 4]);
      s[nt] = __builtin_amdgcn_mfma_f32_16x16x16bf16_1k(kf, qf, zero, 0, 0, 0);
    }
    if (diag) {
#pragma unroll
      for (int nt = 0; nt < 8; nt++)
#pragma unroll
        for (int r = 0; r < 4; r++) {
          int jg = jt * 128 + nt * 16 + g * 4 + r;
          if (jg > qg) s[nt][r] = NEG_BIG;
        }
    }
    f32x4 vm = s[0];
#pragma unroll
    for (int nt = 1; nt < 8; nt++)
#pragma unroll
      for (int r = 0; r < 4; r++) vm[r] = fmaxf(vm[r], s[nt][r]);
    float rm = fmaxf(fmaxf(vm[0], vm[1]), fmaxf(vm[2], vm[3]));
    rm = fmaxf(rm, __shfl_xor(rm, 16, 64));
    rm = fmaxf(rm, __shfl_xor(rm, 32, 64));
    float mnew = fmaxf(mi, rm);
    float alpha = __expf(mi - mnew);
    mi = mnew;
    f32x4 vs = zero;
#pragma unroll
    for (int nt = 0; nt < 8; nt++)
#pragma unroll
      for (int r = 0; r < 4; r++) {
        float pv = __expf(s[nt][r] - mnew);
        s[nt][r] = pv;
        vs[r] += pv;
      }
    float rs = (vs[0] + vs[1]) + (vs[2] + vs[3]);
    rs += __shfl_xor(rs, 16, 64);
    rs += __shfl_xor(rs, 32, 64);
    li = li * alpha + rs;
    float av[4];
#pragma unroll
    for (int r = 0; r < 4; r++) av[r] = __shfl(alpha, srcl + r, 64);
#pragma unroll
    for (int nd = 0; nd < 4; nd++)
#pragma unroll
      for (int r = 0; r < 4; r++) oa[nd][r] *= av[r];
#pragma unroll
    for (int kc = 0; kc < 8; kc++) {
      short4v af = pack_bf16x4(s[kc][0], s[kc][1], s[kc][2], s[kc][3]);
#pragma unroll
      for (int nd = 0; nd < 4; nd++) {
        uint2 vv = *(const uint2*)&Vb[(kc * 4 + g) * 264 + (nd * 16 + c) * 4];
        short4v vf = __builtin_bit_cast(short4v, vv);
        oa[nd] = __builtin_amdgcn_mfma_f32_16x16x16bf16_1k(af, vf, oa[nd], 0, 0, 0);
      }
    }
  };

  int p = 0;
  for (int jt = 0; jt <= jmaxB; jt++) {
    // store prefetched tile into buf p (safe: consumers of buf p finished 2 iters
    // ago, ordered by last iteration's barrier)
    *(uint4*)&Ks[p][(tid >> 1) * 20 + (tid & 1) * 8] = kr;
#pragma unroll
    for (int q = 0; q < 4; q++) {
      int e = (q * 256 + tid) * 8;
      *(uint4*)&Vs[p][(e >> 8) * 264 + (e & 255)] = vr[q];
    }
    __syncthreads();
    if (jt < jmaxB) {                    // issue next-tile loads; fly under compute
      kr = *(const uint4*)&klr[kb + (size_t)(jt + 1) * 2048 + tid * 8];
      const unsigned short* vp = &vt[vb + (size_t)(jt + 1) * 8192];
#pragma unroll
      for (int q = 0; q < 4; q++)
        vr[q] = *(const uint4*)&vp[(q * 256 + tid) * 8];
    }
    compute_tile(qfB, oaB, miB, liB, qgB, jt == jmaxB, jt, p);
    if (jt <= jmaxA) compute_tile(qfA, oaA, miA, liA, qgA, jt == jmaxA, jt, p);
    p ^= 1;
  }

  // epilogue: O in natural orientation; fold 1/li (per-q broadcast) and store
#pragma unroll
  for (int phase = 0; phase < 2; phase++) {
    const f32x4* oa = phase ? oaA : oaB;
    float inv = 1.f / (phase ? liA : liB);   // per q=c
    int q0 = phase ? q0A : q0B;
    float iv[4];
#pragma unroll
    for (int r = 0; r < 4; r++) iv[r] = __shfl(inv, srcl + r, 64);
#pragma unroll
    for (int r = 0; r < 4; r++) {
      size_t rowb = ((size_t)b * TT + q0 + w * 16 + g * 4 + r) * DD + h * 64;
#pragma unroll
      for (int nd = 0; nd < 4; nd++)
        attn[rowb + nd * 16 + c] = f2bf(oa[nd][r] * iv[r]);
    }
  }
}

extern "C" void kernel_launch(void* const* d_in, const int* in_sizes, int n_in,
                              void* d_out, int out_size, void* d_ws, size_t ws_size,
                              hipStream_t stream) {
  const float* x      = (const float*)d_in[0];  // (B,T,1024) fp32
  const float* W_qkv  = (const float*)d_in[1];  // (1024,3072) fp32
  const float* W_qlsr = (const float*)d_in[2];  // (16,64,16)  fp32
  const float* W_klsr = (const float*)d_in[3];  // (16,64,16)  fp32
  const float* core   = (const float*)d_in[4];  // (16,16)     fp32
  const float* W_o    = (const float*)d_in[5];  // (1024,1024) fp32
  float* out = (float*)d_out;                   // (B,T,1024)  fp32

  char* ws = (char*)d_ws;
  unsigned short* x_bf    = (unsigned short*)ws; ws += (size_t)BT * DD * 2;
  unsigned short* Wcomb_t = (unsigned short*)ws; ws += (size_t)NC * DD * 2;
  unsigned short* Wo_t    = (unsigned short*)ws; ws += (size_t)DD * DD * 2;
  unsigned short* qls     = (unsigned short*)ws; ws += (size_t)BH * TT * 16 * 2;
  unsigned short* klr     = (unsigned short*)ws; ws += (size_t)BH * TT * 16 * 2;
  unsigned short* vt      = (unsigned short*)ws; ws += (size_t)BH * TT * 64 * 2;
  unsigned short* attn    = (unsigned short*)ws; ws += (size_t)BT * DD * 2;

  cvt_f32_bf16<<<(BT * DD) / (256 * 8), 256, 0, stream>>>(x, x_bf, BT * DD);
  transpose_cvt<<<dim3(32, 32), dim3(32, 8), 0, stream>>>(W_o, Wo_t, DD, DD, 0);
  transpose_cvt<<<dim3(32, 32), dim3(32, 8), 0, stream>>>(W_qkv, Wcomb_t, DD, D3, 2048);
  build_lsr<<<dim3(16, 16), 256, 0, stream>>>(W_qkv, W_qlsr, W_klsr, core, Wcomb_t);
  gemm_fused<<<dim3(NC / 128, BT / 64), 256, 0, stream>>>(x_bf, Wcomb_t, qls, klr, vt, BT, NC, DD);
  flash_lsr<<<dim3(16, BH), 256, 0, stream>>>(qls, klr, vt, attn);
  gemm64_f32<<<dim3(DD / 128, BT / 64), 256, 0, stream>>>(attn, Wo_t, out, BT, DD, DD);
}

// Round 10
// 194.929 us; speedup vs baseline: 1.6376x; 1.0198x over previous
//
#include <hip/hip_runtime.h>
#include <hip/hip_bf16.h>

// Problem constants
#define BB 2
#define TT 2048
#define DD 1024
#define HH 16
#define DH 64
#define RR 16
#define BT (BB*TT)      // 4096
#define BH (BB*HH)      // 32
#define D3 (3*DD)       // 3072
#define NC 1536         // fused GEMM1 N: 1024 V + 256 q_lr + 256 k_lr

typedef __bf16 bf16x8 __attribute__((ext_vector_type(8)));
typedef float f32x4 __attribute__((ext_vector_type(4)));
typedef short short4v __attribute__((ext_vector_type(4)));

__device__ __forceinline__ float bf2f(unsigned short u) {
  unsigned int v = ((unsigned int)u) << 16;
  return __builtin_bit_cast(float, v);
}
__device__ __forceinline__ unsigned short f2bf(float f) {
  unsigned int x = __builtin_bit_cast(unsigned int, f);
  unsigned int r = x + 0x7fffu + ((x >> 16) & 1u);
  return (unsigned short)(r >> 16);
}
__device__ __forceinline__ short4v pack_bf16x4(float a, float b, float c, float d) {
  uint2 u;
  u.x = (unsigned)f2bf(a) | ((unsigned)f2bf(b) << 16);
  u.y = (unsigned)f2bf(c) | ((unsigned)f2bf(d) << 16);
  return __builtin_bit_cast(short4v, u);
}

#define NEG_BIG (-1e30f)

__device__ __forceinline__ void async_copy16(const void* g, void* l) {
  __builtin_amdgcn_global_load_lds((const __attribute__((address_space(1))) void*)g,
                                   (__attribute__((address_space(3))) void*)l, 16, 0, 0);
}

// ---------------- fp32 -> bf16 elementwise convert ---------------------------------
__global__ __launch_bounds__(256) void cvt_f32_bf16(const float* __restrict__ in,
                                                    unsigned short* __restrict__ out,
                                                    int n) {
  int i = (blockIdx.x * 256 + threadIdx.x) * 8;
  if (i >= n) return;
  float4 a = *(const float4*)&in[i];
  float4 b = *(const float4*)&in[i + 4];
  unsigned short t[8] = {f2bf(a.x), f2bf(a.y), f2bf(a.z), f2bf(a.w),
                         f2bf(b.x), f2bf(b.y), f2bf(b.z), f2bf(b.w)};
  *(uint4*)&out[i] = *(const uint4*)t;
}

// ---------------- transpose+cvt: out[j][d] = in[d][coff+j], fp32->bf16 --------------
__global__ __launch_bounds__(256) void transpose_cvt(const float* __restrict__ in,
                                                     unsigned short* __restrict__ out,
                                                     int R, int C, int coff) {
  __shared__ float tile[32][33];
  const int tx = threadIdx.x, ty = threadIdx.y;
  const int x = blockIdx.x * 32 + tx;
  const int y0 = blockIdx.y * 32;
#pragma unroll
  for (int i = 0; i < 32; i += 8)
    tile[ty + i][tx] = in[(size_t)(y0 + ty + i) * C + coff + x];
  __syncthreads();
  const int xo = y0 + tx;
  const int yo0 = blockIdx.x * 32;
#pragma unroll
  for (int i = 0; i < 32; i += 8)
    out[(size_t)(yo0 + ty + i) * R + xo] = f2bf(tile[tx][ty + i]);
}

// ---------------- combined LSR weights: Wcomb rows 1024..1535 ----------------------
__global__ __launch_bounds__(256) void build_lsr(const float* __restrict__ Wqkv,
                                                 const float* __restrict__ Wql,
                                                 const float* __restrict__ Wkl,
                                                 const float* __restrict__ core,
                                                 unsigned short* __restrict__ Wcomb_t) {
  const int d0 = blockIdx.x * 64, h = blockIdx.y, tid = threadIdx.x;
  __shared__ float Aq[64][65], Ak[64][65], Lq[64][16], Lk[64][16], cs[16];
#pragma unroll
  for (int p = 0; p < 16; p++) {
    int idx = p * 256 + tid, dd = idx >> 6, e = idx & 63;
    Aq[dd][e] = Wqkv[(size_t)(d0 + dd) * D3 + h * 64 + e];
    Ak[dd][e] = Wqkv[(size_t)(d0 + dd) * D3 + DD + h * 64 + e];
  }
#pragma unroll
  for (int p = 0; p < 4; p++) {
    int idx = p * 256 + tid, e = idx >> 4, r = idx & 15;
    Lq[e][r] = Wql[h * 1024 + e * 16 + r];
    Lk[e][r] = Wkl[h * 1024 + e * 16 + r];
  }
  if (tid < 16) cs[tid] = core[h * 16 + tid];
  __syncthreads();
  const int dd = tid & 63, rg = tid >> 6;
  float aq[4] = {}, ak[4] = {};
  for (int e = 0; e < 64; e++) {
    float xq = Aq[dd][e], xk = Ak[dd][e];
#pragma unroll
    for (int j = 0; j < 4; j++) {
      aq[j] += xq * Lq[e][rg * 4 + j];
      ak[j] += xk * Lk[e][rg * 4 + j];
    }
  }
#pragma unroll
  for (int j = 0; j < 4; j++) {
    int r = rg * 4 + j;
    Wcomb_t[(size_t)(1024 + h * 16 + r) * DD + d0 + dd] = f2bf(aq[j] * cs[r] * 0.25f);
    Wcomb_t[(size_t)(1280 + h * 16 + r) * DD + d0 + dd] = f2bf(ak[j]);
  }
}

// ---------------- bf16 GEMM core: 64x128 tile, BK=32, 4 waves 2x2, acc[2][4] --------
__device__ __forceinline__ void gemm64_core(const unsigned short* __restrict__ A,
                                            const unsigned short* __restrict__ Bt,
                                            int K, int bm, int bn,
                                            int tid, int g, int c, int wm, int wn,
                                            f32x4 acc[2][4]) {
  __shared__ __attribute__((aligned(16))) unsigned short As[64 * 32];
  __shared__ __attribute__((aligned(16))) unsigned short Bs[128 * 32];
  const int e0 = tid * 8;
  const int r0 = e0 >> 5, q0 = e0 & 31;
  const unsigned short* Arow = &A[(size_t)(bm * 64 + r0) * K + q0];
  const unsigned short* Brow0 = &Bt[(size_t)(bn * 128 + r0) * K + q0];
  const unsigned short* Brow1 = &Bt[(size_t)(bn * 128 + 64 + r0) * K + q0];
  for (int k0 = 0; k0 < K; k0 += 32) {
    __syncthreads();
    async_copy16(Arow + k0, &As[e0]);
    async_copy16(Brow0 + k0, &Bs[e0]);
    async_copy16(Brow1 + k0, &Bs[2048 + e0]);
    __syncthreads();
    bf16x8 af[2];
#pragma unroll
    for (int mt = 0; mt < 2; mt++)
      af[mt] = *(const bf16x8*)&As[(wm * 32 + mt * 16 + c) * 32 + g * 8];
#pragma unroll
    for (int nt = 0; nt < 4; nt++) {
      bf16x8 bf = *(const bf16x8*)&Bs[(wn * 64 + nt * 16 + c) * 32 + g * 8];
#pragma unroll
      for (int mt = 0; mt < 2; mt++)
        acc[mt][nt] = __builtin_amdgcn_mfma_f32_16x16x32_bf16(af[mt], bf, acc[mt][nt], 0, 0, 0);
    }
  }
}

// gemm2: C fp32 row-major
__global__ __launch_bounds__(256) void gemm64_f32(const unsigned short* __restrict__ A,
                                                  const unsigned short* __restrict__ Bt,
                                                  float* __restrict__ C,
                                                  int M, int N, int K) {
  const int tid = threadIdx.x, lane = tid & 63;
  const int g = lane >> 4, c = lane & 15;
  const int wid = tid >> 6, wm = wid >> 1, wn = wid & 1;
  const int bm = blockIdx.y, bn = blockIdx.x;
  f32x4 acc[2][4] = {};
  gemm64_core(A, Bt, K, bm, bn, tid, g, c, wm, wn, acc);
#pragma unroll
  for (int mt = 0; mt < 2; mt++)
#pragma unroll
    for (int nt = 0; nt < 4; nt++)
#pragma unroll
      for (int r = 0; r < 4; r++) {
        int row = bm * 64 + wm * 32 + mt * 16 + g * 4 + r;
        int col = bn * 128 + wn * 64 + nt * 16 + c;
        C[(size_t)row * N + col] = acc[mt][nt][r];
      }
}

// gemm1 fused: A = x_bf (4096x1024), Bt = Wcomb_t (1536x1024).
__global__ __launch_bounds__(256) void gemm_fused(const unsigned short* __restrict__ A,
                                                  const unsigned short* __restrict__ Bt,
                                                  unsigned short* __restrict__ qls,
                                                  unsigned short* __restrict__ klr,
                                                  unsigned short* __restrict__ vt,
                                                  int M, int N, int K) {
  const int tid = threadIdx.x, lane = tid & 63;
  const int g = lane >> 4, c = lane & 15;
  const int wid = tid >> 6, wm = wid >> 1, wn = wid & 1;
  const int bm = blockIdx.y, bn = blockIdx.x;
  f32x4 acc[2][4] = {};
  gemm64_core(A, Bt, K, bm, bn, tid, g, c, wm, wn, acc);
#pragma unroll
  for (int mt = 0; mt < 2; mt++)
#pragma unroll
    for (int nt = 0; nt < 4; nt++) {
      int colb = bn * 128 + wn * 64 + nt * 16;        // + c
      int tg0 = bm * 64 + wm * 32 + mt * 16 + g * 4;  // tokens tg0..tg0+3 (4-aligned)
      int b = tg0 >> 11, t0 = tg0 & 2047;
      if (colb < 1024) {
        int h = colb >> 6, d = (colb & 63) + c;
        uint2 pk = __builtin_bit_cast(uint2, pack_bf16x4(acc[mt][nt][0], acc[mt][nt][1],
                                                         acc[mt][nt][2], acc[mt][nt][3]));
        size_t idx = (size_t)(b * 16 + h) * (TT / 4) * 256 + (size_t)(t0 >> 2) * 256 + d * 4;
        *(uint2*)&vt[idx] = pk;
      } else if (colb < 1280) {
        int h = (colb - 1024) >> 4;
        size_t base = (size_t)(b * 16 + h) * TT;
#pragma unroll
        for (int r = 0; r < 4; r++)
          qls[(base + t0 + r) * 16 + c] = f2bf(acc[mt][nt][r]);
      } else {
        int h = (colb - 1280) >> 4;
        size_t base = (size_t)(b * 16 + h) * TT;
#pragma unroll
        for (int r = 0; r < 4; r++)
          klr[(base + t0 + r) * 16 + c] = f2bf(acc[mt][nt][r]);
      }
    }
}

// ---------------- Flash attention v7: paired + dbuf + PHASE-INTERLEAVED A/B ---------
// grid (16, BH), 256 thr = 4 waves. Block z handles Q-tiles B=(31-z) and A=z.
// Phase 1 (jt<=jmaxA): BOTH tiles processed through QK/softmax/PV with chains
// textually adjacent (latency overlap). Phase 2: B only. jmaxA < jmaxB always.
// launch_bounds(256,2): VGPR cap 256 so both score arrays stay live.
__global__ __launch_bounds__(256, 2) void flash_lsr(const unsigned short* __restrict__ qls,
                                                    const unsigned short* __restrict__ klr,
                                                    const unsigned short* __restrict__ vt,
                                                    unsigned short* __restrict__ attn) {
  const int z = blockIdx.x;             // 0..15
  const int bh = blockIdx.y, b = bh >> 4, h = bh & 15;
  const int tid = threadIdx.x, lane = tid & 63, w = tid >> 6;
  const int g = lane >> 4, c = lane & 15;
  const int q0_[2] = {(31 - z) * 64, z * 64};          // [0]=B (long), [1]=A (short)
  const int jmax_[2] = {(31 - z) >> 1, z >> 1};

  __shared__ __attribute__((aligned(16))) unsigned short Ks[2][128 * 20];  // 2x5.0 KB
  __shared__ __attribute__((aligned(16))) unsigned short Vs[2][32 * 264];  // 2x16.5 KB

  const size_t qbase = (size_t)bh * TT;
  short4v qf_[2];
  int qg_[2];
  float mi_[2], li_[2];
  f32x4 oa_[2][4] = {};
#pragma unroll
  for (int t = 0; t < 2; t++) {
    qf_[t] = __builtin_bit_cast(short4v,
        *(const uint2*)&qls[(qbase + q0_[t] + w * 16 + c) * 16 + g * 4]);
    qg_[t] = q0_[t] + w * 16 + c;
    mi_[t] = NEG_BIG;
    li_[t] = 0.f;
  }
  const f32x4 zero = {0.f, 0.f, 0.f, 0.f};
  const size_t kb = (size_t)bh * TT * 16;
  const size_t vb = (size_t)bh * TT * 64;
  const int srcl = g * 16 + g * 4;

  // prefetch j-tile 0 into registers
  uint4 kr = *(const uint4*)&klr[kb + tid * 8];
  uint4 vr[4];
#pragma unroll
  for (int p = 0; p < 4; p++)
    vr[p] = *(const uint4*)&vt[vb + (p * 256 + tid) * 8];

  int p = 0;
  f32x4 s_[2][8];

  auto stage = [&](int jt) {
    *(uint4*)&Ks[p][(tid >> 1) * 20 + (tid & 1) * 8] = kr;
#pragma unroll
    for (int q = 0; q < 4; q++) {
      int e = (q * 256 + tid) * 8;
      *(uint4*)&Vs[p][(e >> 8) * 264 + (e & 255)] = vr[q];
    }
    __syncthreads();
    if (jt < jmax_[0]) {
      kr = *(const uint4*)&klr[kb + (size_t)(jt + 1) * 2048 + tid * 8];
      const unsigned short* vp = &vt[vb + (size_t)(jt + 1) * 8192];
#pragma unroll
      for (int q = 0; q < 4; q++)
        vr[q] = *(const uint4*)&vp[(q * 256 + tid) * 8];
    }
  };
  auto qk = [&](int t) {
    const unsigned short* Kb = Ks[p];
#pragma unroll
    for (int nt = 0; nt < 8; nt++) {
      short4v kf = __builtin_bit_cast(short4v, *(const uint2*)&Kb[(nt * 16 + c) * 20 + g * 4]);
      s_[t][nt] = __builtin_amdgcn_mfma_f32_16x16x16bf16_1k(kf, qf_[t], zero, 0, 0, 0);
    }
  };
  auto msk = [&](int t, int jt) {
#pragma unroll
    for (int nt = 0; nt < 8; nt++)
#pragma unroll
      for (int r = 0; r < 4; r++) {
        int jg = jt * 128 + nt * 16 + g * 4 + r;
        if (jg > qg_[t]) s_[t][nt][r] = NEG_BIG;
      }
  };
  auto smax = [&](int t) {
    f32x4 vm = s_[t][0];
#pragma unroll
    for (int nt = 1; nt < 8; nt++)
#pragma unroll
      for (int r = 0; r < 4; r++) vm[r] = fmaxf(vm[r], s_[t][nt][r]);
    float rm = fmaxf(fmaxf(vm[0], vm[1]), fmaxf(vm[2], vm[3]));
    rm = fmaxf(rm, __shfl_xor(rm, 16, 64));
    rm = fmaxf(rm, __shfl_xor(rm, 32, 64));
    float mnew = fmaxf(mi_[t], rm);
    float alpha = __expf(mi_[t] - mnew);
    mi_[t] = mnew;
    f32x4 vs = zero;
#pragma unroll
    for (int nt = 0; nt < 8; nt++)
#pragma unroll
      for (int r = 0; r < 4; r++) {
        float pv = __expf(s_[t][nt][r] - mnew);
        s_[t][nt][r] = pv;
        vs[r] += pv;
      }
    float rs = (vs[0] + vs[1]) + (vs[2] + vs[3]);
    rs += __shfl_xor(rs, 16, 64);
    rs += __shfl_xor(rs, 32, 64);
    li_[t] = li_[t] * alpha + rs;
    float av[4];
#pragma unroll
    for (int r = 0; r < 4; r++) av[r] = __shfl(alpha, srcl + r, 64);
#pragma unroll
    for (int nd = 0; nd < 4; nd++)
#pragma unroll
      for (int r = 0; r < 4; r++) oa_[t][nd][r] *= av[r];
  };
  auto pv = [&](int t) {
    const unsigned short* Vb = Vs[p];
#pragma unroll
    for (int kc = 0; kc < 8; kc++) {
      short4v af = pack_bf16x4(s_[t][kc][0], s_[t][kc][1], s_[t][kc][2], s_[t][kc][3]);
#pragma unroll
      for (int nd = 0; nd < 4; nd++) {
        uint2 vv = *(const uint2*)&Vb[(kc * 4 + g) * 264 + (nd * 16 + c) * 4];
        short4v vf = __builtin_bit_cast(short4v, vv);
        oa_[t][nd] = __builtin_amdgcn_mfma_f32_16x16x16bf16_1k(af, vf, oa_[t][nd], 0, 0, 0);
      }
    }
  };

  int jt = 0;
  for (; jt <= jmax_[1]; jt++) {        // phase 1: both tiles, interleaved chains
    stage(jt);
    qk(0); qk(1);
    if (jt == jmax_[1]) msk(1, jt);     // A diag (B diag impossible here: jmaxA<jmaxB)
    smax(0); smax(1);
    pv(0); pv(1);
    p ^= 1;
  }
  for (; jt <= jmax_[0]; jt++) {        // phase 2: B only
    stage(jt);
    qk(0);
    if (jt == jmax_[0]) msk(0, jt);
    smax(0);
    pv(0);
    p ^= 1;
  }

  // epilogue: O in natural orientation; fold 1/li (per-q broadcast) and store
#pragma unroll
  for (int t = 0; t < 2; t++) {
    float inv = 1.f / li_[t];           // per q=c
    float iv[4];
#pragma unroll
    for (int r = 0; r < 4; r++) iv[r] = __shfl(inv, srcl + r, 64);
#pragma unroll
    for (int r = 0; r < 4; r++) {
      size_t rowb = ((size_t)b * TT + q0_[t] + w * 16 + g * 4 + r) * DD + h * 64;
#pragma unroll
      for (int nd = 0; nd < 4; nd++)
        attn[rowb + nd * 16 + c] = f2bf(oa_[t][nd][r] * iv[r]);
    }
  }
}

extern "C" void kernel_launch(void* const* d_in, const int* in_sizes, int n_in,
                              void* d_out, int out_size, void* d_ws, size_t ws_size,
                              hipStream_t stream) {
  const float* x      = (const float*)d_in[0];  // (B,T,1024) fp32
  const float* W_qkv  = (const float*)d_in[1];  // (1024,3072) fp32
  const float* W_qlsr = (const float*)d_in[2];  // (16,64,16)  fp32
  const float* W_klsr = (const float*)d_in[3];  // (16,64,16)  fp32
  const float* core   = (const float*)d_in[4];  // (16,16)     fp32
  const float* W_o    = (const float*)d_in[5];  // (1024,1024) fp32
  float* out = (float*)d_out;                   // (B,T,1024)  fp32

  char* ws = (char*)d_ws;
  unsigned short* x_bf    = (unsigned short*)ws; ws += (size_t)BT * DD * 2;
  unsigned short* Wcomb_t = (unsigned short*)ws; ws += (size_t)NC * DD * 2;
  unsigned short* Wo_t    = (unsigned short*)ws; ws += (size_t)DD * DD * 2;
  unsigned short* qls     = (unsigned short*)ws; ws += (size_t)BH * TT * 16 * 2;
  unsigned short* klr     = (unsigned short*)ws; ws += (size_t)BH * TT * 16 * 2;
  unsigned short* vt      = (unsigned short*)ws; ws += (size_t)BH * TT * 64 * 2;
  unsigned short* attn    = (unsigned short*)ws; ws += (size_t)BT * DD * 2;

  cvt_f32_bf16<<<(BT * DD) / (256 * 8), 256, 0, stream>>>(x, x_bf, BT * DD);
  transpose_cvt<<<dim3(32, 32), dim3(32, 8), 0, stream>>>(W_o, Wo_t, DD, DD, 0);
  transpose_cvt<<<dim3(32, 32), dim3(32, 8), 0, stream>>>(W_qkv, Wcomb_t, DD, D3, 2048);
  build_lsr<<<dim3(16, 16), 256, 0, stream>>>(W_qkv, W_qlsr, W_klsr, core, Wcomb_t);
  gemm_fused<<<dim3(NC / 128, BT / 64), 256, 0, stream>>>(x_bf, Wcomb_t, qls, klr, vt, BT, NC, DD);
  flash_lsr<<<dim3(16, BH), 256, 0, stream>>>(qls, klr, vt, attn);
  gemm64_f32<<<dim3(DD / 128, BT / 64), 256, 0, stream>>>(attn, Wo_t, out, BT, DD, DD);
}